// Round 2
// baseline (619.375 us; speedup 1.0000x reference)
//
#include <hip/hip_runtime.h>
#include <hip/hip_bf16.h>
#include <math.h>

typedef __hip_bfloat16 bf16;
typedef __attribute__((ext_vector_type(8))) short short8;
typedef __attribute__((ext_vector_type(4))) float float4_;
typedef __attribute__((ext_vector_type(4))) int int4_;

#define B_   2
#define T_   2048
#define D_   1024
#define H_   16
#define NTOK (B_ * T_)
// 0.125 * log2(e): folded into q-side RMSNorm weight so attn uses raw exp2.
#define QSCALE 0.18033688011112042f

#define AS1 __attribute__((address_space(1)))
#define AS3 __attribute__((address_space(3)))

static __device__ __forceinline__ float b2f(bf16 v) { return __bfloat162float(v); }
static __device__ __forceinline__ bf16  f2b(float v) { return __float2bfloat16(v); }
static __device__ __forceinline__ short f2s(float v) {  // fp32 -> bf16 bits (RNE)
    unsigned u = __builtin_bit_cast(unsigned, v);
    unsigned r = (u + 0x7FFFu + ((u >> 16) & 1u)) >> 16;
    return (short)r;
}
static __device__ __forceinline__ float to_f(float v) { return v; }
static __device__ __forceinline__ float to_f(bf16 v) { return __bfloat162float(v); }
static __device__ __forceinline__ void  store_o(float* p, float v) { *p = v; }
static __device__ __forceinline__ void  store_o(bf16* p, float v) { *p = __float2bfloat16(v); }
static __device__ __forceinline__ void gl_lds16(const void* g, void* l) {
    __builtin_amdgcn_global_load_lds((const AS1 unsigned int*)g, (AS3 unsigned int*)l, 16, 0, 0);
}

// ---------------- RMSNorm over D=1024 (one block per token), fp32 in, bf16 out
__global__ __launch_bounds__(256) void rmsnorm_k(const float* __restrict__ x,
                                                 const float* __restrict__ w,
                                                 bf16* __restrict__ out) {
    int t = blockIdx.x, tid = threadIdx.x;
    float xs[4], ss = 0.f;
#pragma unroll
    for (int i = 0; i < 4; ++i) {
        float v = x[(size_t)t * D_ + tid + i * 256];
        xs[i] = v; ss += v * v;
    }
    __shared__ float red[4];
#pragma unroll
    for (int off = 32; off > 0; off >>= 1) ss += __shfl_xor(ss, off, 64);
    if ((tid & 63) == 0) red[tid >> 6] = ss;
    __syncthreads();
    ss = red[0] + red[1] + red[2] + red[3];
    float inv = rsqrtf(ss * (1.f / D_) + 1e-6f);
#pragma unroll
    for (int i = 0; i < 4; ++i) {
        int c = tid + i * 256;
        out[(size_t)t * D_ + c] = f2b(xs[i] * inv * w[c]);
    }
}

// ------- fused modulate (x = x*(1+scale1)+shift1, in place fp32) + RMSNorm2 --
__global__ __launch_bounds__(256) void modnorm_k(float* __restrict__ x1,
                                                 const bf16* __restrict__ mod, // [NTOK][2048] = shift|scale
                                                 const float* __restrict__ w,
                                                 bf16* __restrict__ h2) {
    int t = blockIdx.x, tid = threadIdx.x;
    float xs[4], ss = 0.f;
#pragma unroll
    for (int i = 0; i < 4; ++i) {
        int c = tid + i * 256;
        float sh = b2f(mod[(size_t)t * 2048 + c]);
        float sc = b2f(mod[(size_t)t * 2048 + 1024 + c]);
        float v = x1[(size_t)t * D_ + c] * (1.f + sc) + sh;
        xs[i] = v; ss += v * v;
        x1[(size_t)t * D_ + c] = v;
    }
    __shared__ float red[4];
#pragma unroll
    for (int off = 32; off > 0; off >>= 1) ss += __shfl_xor(ss, off, 64);
    if ((tid & 63) == 0) red[tid >> 6] = ss;
    __syncthreads();
    ss = red[0] + red[1] + red[2] + red[3];
    float inv = rsqrtf(ss * (1.f / D_) + 1e-6f);
#pragma unroll
    for (int i = 0; i < 4; ++i) {
        int c = tid + i * 256;
        h2[(size_t)t * D_ + c] = f2b(xs[i] * inv * w[c]);
    }
}

// ------------- ae1: [NTOK,16] @ [16,1024] + b, SiLU (fp32 in, bf16 out) -----
__global__ __launch_bounds__(256) void ae1_k(const float* __restrict__ actions,
                                             const float* __restrict__ w,
                                             const float* __restrict__ b,
                                             bf16* __restrict__ out) {
    int t = blockIdx.x, tid = threadIdx.x;
    float av[16];
#pragma unroll
    for (int a = 0; a < 16; ++a) av[a] = actions[(size_t)t * 16 + a];
#pragma unroll
    for (int i = 0; i < 4; ++i) {
        int n = tid + i * 256;
        float acc = b[n];
#pragma unroll
        for (int a = 0; a < 16; ++a) acc += av[a] * w[a * D_ + n];
        out[(size_t)t * D_ + n] = f2b(acc / (1.f + expf(-acc)));
    }
}

// ---- weight prep: fp32 W[K][N] (row stride ldw) -> bf16 WT[N][K], fused -----
struct WD { const float* src; bf16* dst; int K, N, ldw, tiles; };
struct WPack { WD d[8]; };
__global__ __launch_bounds__(256) void wprep_k(WPack p) {
    int bid = blockIdx.x;
    int mi = 0, cum = 0;
#pragma unroll
    for (mi = 0; mi < 8; ++mi) {
        if (bid < cum + p.d[mi].tiles) break;
        cum += p.d[mi].tiles;
    }
    if (mi >= 8) return;
    WD w = p.d[mi];
    int local = bid - cum;
    int tilesK = w.K >> 6;
    int tk = local % tilesK, tn = local / tilesK;
    int k0 = tk * 64, n0 = tn * 64;
    __shared__ short Tt[64 * 72];   // [n][k]
    int t = threadIdx.x;
    int row = t >> 2, seg = t & 3;
    const float* sp = w.src + (size_t)(k0 + row) * w.ldw + n0 + seg * 16;
#pragma unroll
    for (int q = 0; q < 4; ++q) {
        float4_ f = *(const float4_*)(sp + q * 4);
#pragma unroll
        for (int j = 0; j < 4; ++j) Tt[(seg * 16 + q * 4 + j) * 72 + row] = f2s(f[j]);
    }
    __syncthreads();
    bf16* dp = w.dst + (size_t)(n0 + row) * w.K + k0 + seg * 16;
    *(short8*)dp       = *(const short8*)&Tt[row * 72 + seg * 16];
    *(short8*)(dp + 8) = *(const short8*)&Tt[row * 72 + seg * 16 + 8];
}

// ---- concat q_b|k_b -> biasQK[2048] -----------------------------------------
__global__ __launch_bounds__(256) void bcat_k(const float* __restrict__ qb,
                                              const float* __restrict__ kb,
                                              float* __restrict__ dst) {
    int i = blockIdx.x * 256 + threadIdx.x;   // grid 8*256 = 2048
    dst[i] = (i < 1024) ? qb[i] : kb[i & 1023];
}

// --------- MFMA GEMM 128x128: C = A[M,K](bf16) @ WT[N,K](bf16) ---------------
// ACT: 0 none, 1 SiLU, 2 GELU(exact). res added after ACT. ldo = out/res stride.
// QKN: fused per-head RMSNorm (HD=64) on packed Q|K output; each wave's 64-col
// span is one head, so a 16-lane shuffle gives the head sum-sq. q-head norm
// weight additionally folds QSCALE so attention softmax is bare exp2.
// BROW: bias indexed by ROW (for the V^T = Wv^T @ h^T GEMM).
template <int ACT, int QKN, int BROW, typename ResT, typename OutT>
__global__ __launch_bounds__(256) void gemm_k(const bf16* __restrict__ A,
                                              const bf16* __restrict__ Bt,
                                              const float* __restrict__ bias,
                                              const ResT* __restrict__ res,
                                              OutT* __restrict__ out,
                                              int M, int N, int K, int ldo,
                                              const float* __restrict__ qn_w,
                                              const float* __restrict__ kn_w) {
    __shared__ __align__(16) short As[128 * 64];
    __shared__ __align__(16) short Bs[128 * 64];
    const int tid = threadIdx.x;
    const int bm = blockIdx.y * 128, bn = blockIdx.x * 128;
    const int wave = tid >> 6, lane = tid & 63;
    const int wm = (wave & 1) * 64, wn = (wave >> 1) * 64;
    const int l15 = lane & 15, quad = lane >> 4;
    const int lrow = lane >> 3, lseg = (lane & 7) * 8;
    float4_ acc[4][4] = {};

    for (int k0 = 0; k0 < K; k0 += 64) {
#pragma unroll
        for (int it = 0; it < 4; ++it) {
            int r = it * 32 + wave * 8;
            gl_lds16((const short*)A + (size_t)(bm + r + lrow) * K + k0 + lseg, &As[r * 64]);
            gl_lds16((const short*)Bt + (size_t)(bn + r + lrow) * K + k0 + lseg, &Bs[r * 64]);
        }
        __syncthreads();
#pragma unroll
        for (int kk = 0; kk < 64; kk += 32) {
            short8 af[4], bfr[4];
#pragma unroll
            for (int i = 0; i < 4; ++i)
                af[i] = *(const short8*)&As[(wm + i * 16 + l15) * 64 + kk + quad * 8];
#pragma unroll
            for (int j = 0; j < 4; ++j)
                bfr[j] = *(const short8*)&Bs[(wn + j * 16 + l15) * 64 + kk + quad * 8];
#pragma unroll
            for (int i = 0; i < 4; ++i)
#pragma unroll
                for (int j = 0; j < 4; ++j)
                    acc[i][j] = __builtin_amdgcn_mfma_f32_16x16x32_bf16(af[i], bfr[j], acc[i][j], 0, 0, 0);
        }
        __syncthreads();
    }

    int seg = (bn + wn) >> 10;               // QKN: 0=q, 1=k
    float nwv[4];
    if (QKN && seg < 2) {
        const float* nw = seg ? kn_w : qn_w;
        float qsc = seg ? 1.f : QSCALE;
#pragma unroll
        for (int j = 0; j < 4; ++j) nwv[j] = nw[j * 16 + l15] * qsc;
    }

#pragma unroll
    for (int i = 0; i < 4; ++i) {
        float vv[4][4];
        float bvr[4];
        if (BROW) {
#pragma unroll
            for (int r = 0; r < 4; ++r) bvr[r] = bias[bm + wm + i * 16 + quad * 4 + r];
        }
#pragma unroll
        for (int j = 0; j < 4; ++j) {
            float bv = BROW ? 0.f : bias[bn + wn + j * 16 + l15];
#pragma unroll
            for (int r = 0; r < 4; ++r) vv[j][r] = acc[i][j][r] + (BROW ? bvr[r] : bv);
        }
        if (QKN && seg < 2) {
#pragma unroll
            for (int r = 0; r < 4; ++r) {
                float ss = vv[0][r] * vv[0][r] + vv[1][r] * vv[1][r]
                         + vv[2][r] * vv[2][r] + vv[3][r] * vv[3][r];
#pragma unroll
                for (int off = 8; off > 0; off >>= 1) ss += __shfl_xor(ss, off, 16);
                float inv = rsqrtf(ss * (1.f / 64.f) + 1e-6f);
#pragma unroll
                for (int j = 0; j < 4; ++j) vv[j][r] *= inv * nwv[j];
            }
        }
#pragma unroll
        for (int j = 0; j < 4; ++j) {
            int col = bn + wn + j * 16 + l15;
#pragma unroll
            for (int r = 0; r < 4; ++r) {
                int row = bm + wm + i * 16 + quad * 4 + r;
                float v = vv[j][r];
                if (ACT == 1) v = v / (1.f + expf(-v));
                else if (ACT == 2) v = 0.5f * v * (1.f + erff(v * 0.70710678118654752f));
                if (res) v += to_f(res[(size_t)row * ldo + col]);
                store_o(&out[(size_t)row * ldo + col], v);
            }
        }
    }
}

// --------- MFMA GEMM 64x128 tile: for N=1024 GEMMs (512 blocks = 2/CU) -------
template <int ACT, typename ResT, typename OutT>
__global__ __launch_bounds__(256) void gemm64_k(const bf16* __restrict__ A,
                                                const bf16* __restrict__ Bt,
                                                const float* __restrict__ bias,
                                                const ResT* __restrict__ res,
                                                OutT* __restrict__ out,
                                                int M, int N, int K) {
    __shared__ __align__(16) short As[64 * 64];
    __shared__ __align__(16) short Bs[128 * 64];
    const int tid = threadIdx.x;
    const int bm = blockIdx.y * 64, bn = blockIdx.x * 128;
    const int wave = tid >> 6, lane = tid & 63;
    const int wm = (wave & 1) * 32, wn = (wave >> 1) * 64;
    const int l15 = lane & 15, quad = lane >> 4;
    const int lrow = lane >> 3, lseg = (lane & 7) * 8;
    float4_ acc[2][4] = {};

    for (int k0 = 0; k0 < K; k0 += 64) {
#pragma unroll
        for (int it = 0; it < 2; ++it) {
            int r = wave * 16 + it * 8;
            gl_lds16((const short*)A + (size_t)(bm + r + lrow) * K + k0 + lseg, &As[r * 64]);
        }
#pragma unroll
        for (int it = 0; it < 4; ++it) {
            int r = it * 32 + wave * 8;
            gl_lds16((const short*)Bt + (size_t)(bn + r + lrow) * K + k0 + lseg, &Bs[r * 64]);
        }
        __syncthreads();
#pragma unroll
        for (int kk = 0; kk < 64; kk += 32) {
            short8 af[2], bfr[4];
#pragma unroll
            for (int i = 0; i < 2; ++i)
                af[i] = *(const short8*)&As[(wm + i * 16 + l15) * 64 + kk + quad * 8];
#pragma unroll
            for (int j = 0; j < 4; ++j)
                bfr[j] = *(const short8*)&Bs[(wn + j * 16 + l15) * 64 + kk + quad * 8];
#pragma unroll
            for (int i = 0; i < 2; ++i)
#pragma unroll
                for (int j = 0; j < 4; ++j)
                    acc[i][j] = __builtin_amdgcn_mfma_f32_16x16x32_bf16(af[i], bfr[j], acc[i][j], 0, 0, 0);
        }
        __syncthreads();
    }

#pragma unroll
    for (int i = 0; i < 2; ++i)
#pragma unroll
        for (int j = 0; j < 4; ++j) {
            int col = bn + wn + j * 16 + l15;
            float bv = bias[col];
#pragma unroll
            for (int r = 0; r < 4; ++r) {
                int row = bm + wm + i * 16 + quad * 4 + r;
                float v = acc[i][j][r] + bv;
                if (ACT == 1) v = v / (1.f + expf(-v));
                else if (ACT == 2) v = 0.5f * v * (1.f + erff(v * 0.70710678118654752f));
                if (res) v += to_f(res[(size_t)row * N + col]);
                store_o(&out[(size_t)row * N + col], v);
            }
        }
}

// -------------- flash attention, causal, HD=64, q-tile 16/wave, KV tile 64 ---
// ZERO LDS / ZERO BARRIERS. Swapped QK^T (mfma(K,Q)) puts a full P row per
// lane-column; P is rebuilt into A-fragments IN REGISTERS via cvt_pk_bf16 +
// 12 shfl_xor (masks 16/32/48). V is consumed pre-transposed from the VT GEMM
// output [1024 hd][4096 tok] with coalesced 16B fragment loads. NO-MAX
// softmax (qk-RMSNorm bounds |s|<=~11.6 in exp2 units) -> partial (O,l)
// combine linearly across KV chunks. Q pre-scaled by 0.125*log2e.
// chunk slot prefix (chunks only for qb >= 1<<CSH):
template <int CSH>
static __device__ __forceinline__ int chunk_base2(int qb) {
    int g = qb >> CSH, S = 1 << CSH;
    return (g == 0) ? 0 : S * ((g - 1) * (g + 2) / 2) + (qb & (S - 1)) * (g + 1);
}

template <int SPLIT, int CSH>
__global__ __launch_bounds__(256, 4) void attn_k(const bf16* __restrict__ QK,  // [NTOK][2048] q|k
                                                 const bf16* __restrict__ VT,  // [1024][4096]
                                                 bf16* __restrict__ O,
                                                 float* __restrict__ OP,
                                                 float* __restrict__ LP) {
    const int bh = blockIdx.y, b = bh >> 4, h = bh & 15;
    int qb, ci;
    if (SPLIT) {
        int rem = blockIdx.x; qb = 31; ci = 0;
        for (;;) { int ncq = (qb >> CSH) + 1; if (rem < ncq) { ci = rem; break; } rem -= ncq; --qb; }
    } else { qb = 31 - (int)blockIdx.x; ci = 0; }
    const int n   = qb + 1;                          // causal KV tiles for qb
    const int nc  = SPLIT ? ((qb >> CSH) + 1) : 1;
    const int bsz = n / nc, rem2 = n - bsz * nc;     // balanced chunk sizes
    const int t0  = ci * bsz + (ci < rem2 ? ci : rem2);
    const int t1  = t0 + bsz + (ci < rem2 ? 1 : 0);
    const int q0  = qb * 64;
    const int tid = threadIdx.x, wave = tid >> 6, lane = tid & 63;
    const int l15 = lane & 15, quad = lane >> 4;

    const short* Qp = (const short*)QK + (size_t)b * T_ * 2048 + h * 64;
    const short* Kp = Qp + 1024;
    const short* Vp = (const short*)VT + (size_t)h * 64 * 4096 + b * T_;

    const int qrow = q0 + wave * 16 + l15;           // this lane's q row (col of S^T)
    short8 qf0 = *(const short8*)(Qp + (size_t)qrow * 2048 + quad * 8);
    short8 qf1 = *(const short8*)(Qp + (size_t)qrow * 2048 + 32 + quad * 8);

    float4_ oacc[4] = {};
    float l_r = 0.f;

    for (int t = t0; t < t1; ++t) {
        const int kv0 = t * 64;
        // swapped QK^T: D[row=k-local][col=q-local]; frags same as unswapped
        float4_ s[4];
#pragma unroll
        for (int c = 0; c < 4; ++c) {
            const short* kp = Kp + (size_t)(kv0 + c * 16 + l15) * 2048 + quad * 8;
            short8 kb0 = *(const short8*)kp;
            short8 kb1 = *(const short8*)(kp + 32);
            float4_ sc = {};
            sc = __builtin_amdgcn_mfma_f32_16x16x32_bf16(kb0, qf0, sc, 0, 0, 0);
            sc = __builtin_amdgcn_mfma_f32_16x16x32_bf16(kb1, qf1, sc, 0, 0, 0);
            s[c] = sc;
        }
        // exp2 + per-lane l accumulate; lane holds P(q=l15-row, k=c*16+quad*4+r)
        if (t == qb) {
#pragma unroll
            for (int c = 0; c < 4; ++c)
#pragma unroll
                for (int r = 0; r < 4; ++r) {
                    int kvi = kv0 + c * 16 + quad * 4 + r;
                    float p = __builtin_amdgcn_exp2f(s[c][r]);
                    p = (kvi > qrow) ? 0.f : p;
                    s[c][r] = p; l_r += p;
                }
        } else {
#pragma unroll
            for (int c = 0; c < 4; ++c)
#pragma unroll
                for (int r = 0; r < 4; ++r) {
                    float p = __builtin_amdgcn_exp2f(s[c][r]);
                    s[c][r] = p; l_r += p;
                }
        }
        // pack rows to bf16 pairs: pk[c][0]=(r0,r1) k=c*16+quad*4+{0,1}; [1]={2,3}
        int pk0[4], pk1[4];
#pragma unroll
        for (int c = 0; c < 4; ++c) {
            asm("v_cvt_pk_bf16_f32 %0, %1, %2" : "=v"(pk0[c]) : "v"(s[c][0]), "v"(s[c][1]));
            asm("v_cvt_pk_bf16_f32 %0, %1, %2" : "=v"(pk1[c]) : "v"(s[c][2]), "v"(s[c][3]));
        }
        // rebuild A-fragments in-register: lane(l15,quad) <- P(l15, quad*8+j+32x)
        short8 pa[2];
#pragma unroll
        for (int x = 0; x < 2; ++x) {
            int own0 = (quad & 2) ? pk0[2 * x + 1] : pk0[2 * x];
            int own1 = (quad & 2) ? pk1[2 * x + 1] : pk1[2 * x];
            int oth0 = (quad & 2) ? pk0[2 * x]     : pk0[2 * x + 1];
            int oth1 = (quad & 2) ? pk1[2 * x]     : pk1[2 * x + 1];
            int a16_0 = __shfl_xor(own0, 16, 64), a16_1 = __shfl_xor(own1, 16, 64);
            int a32_0 = __shfl_xor(oth0, 32, 64), a32_1 = __shfl_xor(oth1, 32, 64);
            int a48_0 = __shfl_xor(oth0, 48, 64), a48_1 = __shfl_xor(oth1, 48, 64);
            int u0 = (quad == 0) ? own0  : (quad == 1) ? a48_0 : (quad == 2) ? a32_0 : a16_0;
            int u1 = (quad == 0) ? own1  : (quad == 1) ? a48_1 : (quad == 2) ? a32_1 : a16_1;
            int u2 = (quad == 0) ? a16_0 : (quad == 1) ? a32_0 : (quad == 2) ? a48_0 : own0;
            int u3 = (quad == 0) ? a16_1 : (quad == 1) ? a32_1 : (quad == 2) ? a48_1 : own1;
            int4_ pi = { u0, u1, u2, u3 };
            pa[x] = __builtin_bit_cast(short8, pi);
        }
        // PV: B-frag = V^T direct from global (16B/lane, coalesced)
#pragma unroll
        for (int x = 0; x < 2; ++x)
#pragma unroll
            for (int d = 0; d < 4; ++d) {
                short8 vf = *(const short8*)(Vp + (size_t)(d * 16 + l15) * 4096 + kv0 + x * 32 + quad * 8);
                oacc[d] = __builtin_amdgcn_mfma_f32_16x16x32_bf16(pa[x], vf, oacc[d], 0, 0, 0);
            }
    }

    // l reduction over the quad group: lanes {l15,+16,+32,+48} hold same q
    l_r += __shfl_xor(l_r, 16, 64);
    l_r += __shfl_xor(l_r, 32, 64);

    if (!SPLIT || nc == 1) {
        float linv = 1.f / l_r;                      // lane l15 holds q-local l15
        float lrow[4];
#pragma unroll
        for (int r = 0; r < 4; ++r) lrow[r] = __shfl(linv, quad * 4 + r, 64);
#pragma unroll
        for (int d = 0; d < 4; ++d)
#pragma unroll
            for (int r = 0; r < 4; ++r) {
                int qr = q0 + wave * 16 + quad * 4 + r;
                O[(size_t)(b * T_ + qr) * D_ + h * 64 + d * 16 + l15] = f2b(oacc[d][r] * lrow[r]);
            }
    } else {
        const int SLOTS = chunk_base2<CSH>(32);
        const int slot = bh * SLOTS + chunk_base2<CSH>(qb) + ci;
        float* op = OP + (size_t)slot * 4096;
#pragma unroll
        for (int d = 0; d < 4; ++d)
#pragma unroll
            for (int r = 0; r < 4; ++r)
                op[(wave * 16 + quad * 4 + r) * 64 + d * 16 + l15] = oacc[d][r];
        if (lane < 16) LP[slot * 64 + wave * 16 + lane] = l_r;
    }
}

// --- combine KV-chunk partials: O = (sum_c O_c) / (sum_c l_c), bf16 out ------
template <int CSH>
__global__ __launch_bounds__(256) void comb_k(const float* __restrict__ OP,
                                              const float* __restrict__ LP,
                                              bf16* __restrict__ O) {
    const int qb = (1 << CSH) + (int)blockIdx.x;     // only qb>=1<<CSH chunked
    const int bh = blockIdx.y, b = bh >> 4, h = bh & 15;
    const int nc = (qb >> CSH) + 1;
    const int SLOTS = chunk_base2<CSH>(32);
    const int slot0 = bh * SLOTS + chunk_base2<CSH>(qb);
    const int tid = threadIdx.x;
    const int row = tid >> 2, c0 = (tid & 3) << 4;   // 16 floats per thread
    const float* p = OP + (size_t)slot0 * 4096 + row * 64 + c0;
    float4_ a0 = *(const float4_*)(p + 0);
    float4_ a1 = *(const float4_*)(p + 4);
    float4_ a2 = *(const float4_*)(p + 8);
    float4_ a3 = *(const float4_*)(p + 12);
    float l = LP[slot0 * 64 + row];
    for (int c = 1; c < nc; ++c) {
        const float* q = p + (size_t)c * 4096;
        a0 += *(const float4_*)(q + 0);
        a1 += *(const float4_*)(q + 4);
        a2 += *(const float4_*)(q + 8);
        a3 += *(const float4_*)(q + 12);
        l += LP[(slot0 + c) * 64 + row];
    }
    float inv = 1.f / l;
    short8 w0, w1;
#pragma unroll
    for (int j = 0; j < 4; ++j) {
        w0[j]     = f2s(a0[j] * inv);
        w0[4 + j] = f2s(a1[j] * inv);
        w1[j]     = f2s(a2[j] * inv);
        w1[4 + j] = f2s(a3[j] * inv);
    }
    bf16* o = O + (size_t)(b * T_ + qb * 64 + row) * D_ + h * 64 + c0;
    *(short8*)o       = w0;
    *(short8*)(o + 8) = w1;
}

// ---------------------------------------------------------------------------
// Workspace:
//   Ah[0,8) ; QKp[8,24) ([NTOK][2048] bf16 q|k) ; VT4[24,32) ([1024][4096]) ;
//   AO[32,40) ; after attn+o-proj: AE1[8,16) AES[16,24) MOD[24,40) ;
//   M1G[8,40) after modnorm.
//   weights [40,70): WTqkv 40 WTo 46 WTae2 48 WTmod 50 WTm1 54 WTm2 62
//   biasQK at 70MB; OPART at 70MB+16K; LPART after OPART. X1 lives in d_out.
extern "C" void kernel_launch(void* const* d_in, const int* in_sizes, int n_in,
                              void* d_out, int out_size, void* d_ws, size_t ws_size,
                              hipStream_t stream) {
    const float* x     = (const float*)d_in[0];
    const float* acts  = (const float*)d_in[1];
    const float* n1_w  = (const float*)d_in[2];
    const float* n2_w  = (const float*)d_in[3];
    const float* q_w   = (const float*)d_in[4];
    const float* q_b   = (const float*)d_in[5];
    const float* k_w   = (const float*)d_in[6];
    const float* k_b   = (const float*)d_in[7];
    const float* v_w   = (const float*)d_in[8];
    const float* v_b   = (const float*)d_in[9];
    const float* qn_w  = (const float*)d_in[10];
    const float* kn_w  = (const float*)d_in[11];
    const float* o_w   = (const float*)d_in[12];
    const float* o_b   = (const float*)d_in[13];
    const float* ae1_w = (const float*)d_in[14];
    const float* ae1_b = (const float*)d_in[15];
    const float* ae2_w = (const float*)d_in[16];
    const float* ae2_b = (const float*)d_in[17];
    const float* mod_w = (const float*)d_in[18];
    const float* mod_b = (const float*)d_in[19];
    const float* m1_w  = (const float*)d_in[20];
    const float* m1_b  = (const float*)d_in[21];
    const float* m2_w  = (const float*)d_in[22];
    const float* m2_b  = (const float*)d_in[23];
    float* out = (float*)d_out;

    char* ws = (char*)d_ws;
    const size_t MB = 1ull << 20;
    bf16*  Ah   = (bf16*)(ws + 0);
    bf16*  QKp  = (bf16*)(ws + 8 * MB);    // [NTOK][2048]
    bf16*  VT4  = (bf16*)(ws + 24 * MB);   // [1024][4096]
    bf16*  AO   = (bf16*)(ws + 32 * MB);
    bf16*  AE1  = (bf16*)(ws + 8 * MB);
    bf16*  AES  = (bf16*)(ws + 16 * MB);
    bf16*  MOD  = (bf16*)(ws + 24 * MB);
    bf16*  M1G  = (bf16*)(ws + 8 * MB);
    float* X1   = out;

    bf16* WTqkv = (bf16*)(ws + 40 * MB);   // q|k|v contiguous -> [3072][1024]
    bf16* WTv   = WTqkv + 2048 * 1024;
    bf16* WTo   = (bf16*)(ws + 46 * MB);
    bf16* WTae2 = (bf16*)(ws + 48 * MB);
    bf16* WTmod = (bf16*)(ws + 50 * MB);   // [2048][1024]
    bf16* WTm1  = (bf16*)(ws + 54 * MB);   // [4096][1024]
    bf16* WTm2  = (bf16*)(ws + 62 * MB);   // [1024][4096]
    float* biasQK = (float*)(ws + 70 * MB);
    float* OPART  = (float*)(ws + 70 * MB + 16384);
    // CSH=2: 32*140 slots * 16KB = 73400320 ; CSH=3: 32*72 * 16KB = 37748736
    const size_t base_ws = 70 * MB + 16384;
    const size_t need2 = base_ws + 73400320ull + 32 * 140 * 256ull;
    const size_t need3 = base_ws + 37748736ull + 32 * 72 * 256ull;
    const int mode = (ws_size >= need2) ? 2 : (ws_size >= need3) ? 3 : 0;
    float* LPART = (float*)(ws + base_ws + (mode == 2 ? 73400320ull : 37748736ull));

    dim3 blk(256);

    WPack p;
    p.d[0] = { q_w,   WTqkv,                1024, 1024, 1024, 256 };
    p.d[1] = { k_w,   WTqkv + 1024 * 1024,  1024, 1024, 1024, 256 };
    p.d[2] = { v_w,   WTqkv + 2048 * 1024,  1024, 1024, 1024, 256 };
    p.d[3] = { o_w,   WTo,   1024, 1024, 1024, 256 };
    p.d[4] = { ae2_w, WTae2, 1024, 1024, 1024, 256 };
    p.d[5] = { mod_w, WTmod, 1024, 2048, 4096, 512 };
    p.d[6] = { m1_w,  WTm1,  1024, 4096, 4096, 1024 };
    p.d[7] = { m2_w,  WTm2,  4096, 1024, 1024, 1024 };
    wprep_k<<<3840, blk, 0, stream>>>(p);
    bcat_k<<<8, blk, 0, stream>>>(q_b, k_b, biasQK);

    rmsnorm_k<<<NTOK, blk, 0, stream>>>(x, n1_w, Ah);
    // Q|K projection + fused per-head RMSNorm (q side folds QSCALE)
    gemm_k<0, 1, 0, float, bf16><<<dim3(16, 32), blk, 0, stream>>>(Ah, WTqkv, biasQK, (const float*)nullptr, QKp, NTOK, 2048, 1024, 2048, qn_w, kn_w);
    // V^T = WTv @ Ah^T : [1024 v-cols][4096 tokens], bias per row
    gemm_k<0, 0, 1, float, bf16><<<dim3(32, 8), blk, 0, stream>>>(WTv, Ah, v_b, (const float*)nullptr, VT4, 1024, 4096, 1024, 4096, nullptr, nullptr);
    if (mode == 2) {
        attn_k<1, 2><<<dim3(144, B_ * H_), blk, 0, stream>>>(QKp, VT4, AO, OPART, LPART);
        comb_k<2><<<dim3(28, B_ * H_), blk, 0, stream>>>(OPART, LPART, AO);
    } else if (mode == 3) {
        attn_k<1, 3><<<dim3(80, B_ * H_), blk, 0, stream>>>(QKp, VT4, AO, OPART, LPART);
        comb_k<3><<<dim3(24, B_ * H_), blk, 0, stream>>>(OPART, LPART, AO);
    } else {
        attn_k<0, 3><<<dim3(32, B_ * H_), blk, 0, stream>>>(QKp, VT4, AO, OPART, LPART);
    }
    gemm64_k<0, float, float><<<dim3(8, 64), blk, 0, stream>>>(AO, WTo, o_b, x, X1, NTOK, 1024, 1024);
    ae1_k<<<NTOK, blk, 0, stream>>>(acts, ae1_w, ae1_b, AE1);
    gemm64_k<1, float, bf16><<<dim3(8, 64), blk, 0, stream>>>(AE1, WTae2, ae2_b, (const float*)nullptr, AES, NTOK, 1024, 1024);
    gemm_k<0, 0, 0, float, bf16><<<dim3(16, 32), blk, 0, stream>>>(AES, WTmod, mod_b, (const float*)nullptr, MOD, NTOK, 2048, 1024, 2048, nullptr, nullptr);
    modnorm_k<<<NTOK, blk, 0, stream>>>(X1, MOD, n2_w, Ah);
    gemm_k<2, 0, 0, float, bf16><<<dim3(32, 32), blk, 0, stream>>>(Ah, WTm1, m1_b, (const float*)nullptr, M1G, NTOK, 4096, 1024, 4096, nullptr, nullptr);
    gemm64_k<0, float, float><<<dim3(8, 64), blk, 0, stream>>>(M1G, WTm2, m2_b, X1, out, NTOK, 1024, 4096);
}

// Round 3
// 564.420 us; speedup vs baseline: 1.0974x; 1.0974x over previous
//
#include <hip/hip_runtime.h>
#include <hip/hip_bf16.h>
#include <math.h>

typedef __hip_bfloat16 bf16;
typedef __attribute__((ext_vector_type(8))) short short8;
typedef __attribute__((ext_vector_type(4))) float float4_;

#define B_   2
#define T_   2048
#define D_   1024
#define H_   16
#define NTOK (B_ * T_)
// 0.125 * log2(e): folded into q-side RMSNorm weight so attn uses raw exp2.
#define QSCALE 0.18033688011112042f

#define AS1 __attribute__((address_space(1)))
#define AS3 __attribute__((address_space(3)))

static __device__ __forceinline__ float b2f(bf16 v) { return __bfloat162float(v); }
static __device__ __forceinline__ bf16  f2b(float v) { return __float2bfloat16(v); }
static __device__ __forceinline__ short f2s(float v) {  // fp32 -> bf16 bits (RNE)
    unsigned u = __builtin_bit_cast(unsigned, v);
    unsigned r = (u + 0x7FFFu + ((u >> 16) & 1u)) >> 16;
    return (short)r;
}
static __device__ __forceinline__ float to_f(float v) { return v; }
static __device__ __forceinline__ float to_f(bf16 v) { return __bfloat162float(v); }
static __device__ __forceinline__ void  store_o(float* p, float v) { *p = v; }
static __device__ __forceinline__ void  store_o(bf16* p, float v) { *p = __float2bfloat16(v); }
static __device__ __forceinline__ void gl_lds16(const void* g, void* l) {
    __builtin_amdgcn_global_load_lds((const AS1 unsigned int*)g, (AS3 unsigned int*)l, 16, 0, 0);
}

// ---------------- RMSNorm over D=1024 (one block per token), fp32 in, bf16 out
__global__ __launch_bounds__(256) void rmsnorm_k(const float* __restrict__ x,
                                                 const float* __restrict__ w,
                                                 bf16* __restrict__ out) {
    int t = blockIdx.x, tid = threadIdx.x;
    float xs[4], ss = 0.f;
#pragma unroll
    for (int i = 0; i < 4; ++i) {
        float v = x[(size_t)t * D_ + tid + i * 256];
        xs[i] = v; ss += v * v;
    }
    __shared__ float red[4];
#pragma unroll
    for (int off = 32; off > 0; off >>= 1) ss += __shfl_xor(ss, off, 64);
    if ((tid & 63) == 0) red[tid >> 6] = ss;
    __syncthreads();
    ss = red[0] + red[1] + red[2] + red[3];
    float inv = rsqrtf(ss * (1.f / D_) + 1e-6f);
#pragma unroll
    for (int i = 0; i < 4; ++i) {
        int c = tid + i * 256;
        out[(size_t)t * D_ + c] = f2b(xs[i] * inv * w[c]);
    }
}

// ------- fused modulate (x = x*(1+scale1)+shift1, in place fp32) + RMSNorm2 --
__global__ __launch_bounds__(256) void modnorm_k(float* __restrict__ x1,
                                                 const bf16* __restrict__ mod, // [NTOK][2048] = shift|scale
                                                 const float* __restrict__ w,
                                                 bf16* __restrict__ h2) {
    int t = blockIdx.x, tid = threadIdx.x;
    float xs[4], ss = 0.f;
#pragma unroll
    for (int i = 0; i < 4; ++i) {
        int c = tid + i * 256;
        float sh = b2f(mod[(size_t)t * 2048 + c]);
        float sc = b2f(mod[(size_t)t * 2048 + 1024 + c]);
        float v = x1[(size_t)t * D_ + c] * (1.f + sc) + sh;
        xs[i] = v; ss += v * v;
        x1[(size_t)t * D_ + c] = v;
    }
    __shared__ float red[4];
#pragma unroll
    for (int off = 32; off > 0; off >>= 1) ss += __shfl_xor(ss, off, 64);
    if ((tid & 63) == 0) red[tid >> 6] = ss;
    __syncthreads();
    ss = red[0] + red[1] + red[2] + red[3];
    float inv = rsqrtf(ss * (1.f / D_) + 1e-6f);
#pragma unroll
    for (int i = 0; i < 4; ++i) {
        int c = tid + i * 256;
        h2[(size_t)t * D_ + c] = f2b(xs[i] * inv * w[c]);
    }
}

// ------------- ae1: [NTOK,16] @ [16,1024] + b, SiLU (fp32 in, bf16 out) -----
__global__ __launch_bounds__(256) void ae1_k(const float* __restrict__ actions,
                                             const float* __restrict__ w,
                                             const float* __restrict__ b,
                                             bf16* __restrict__ out) {
    int t = blockIdx.x, tid = threadIdx.x;
    float av[16];
#pragma unroll
    for (int a = 0; a < 16; ++a) av[a] = actions[(size_t)t * 16 + a];
#pragma unroll
    for (int i = 0; i < 4; ++i) {
        int n = tid + i * 256;
        float acc = b[n];
#pragma unroll
        for (int a = 0; a < 16; ++a) acc += av[a] * w[a * D_ + n];
        out[(size_t)t * D_ + n] = f2b(acc / (1.f + expf(-acc)));
    }
}

// ---- weight prep: fp32 W[K][N] (row stride ldw) -> bf16 WT[N][K], fused -----
struct WD { const float* src; bf16* dst; int K, N, ldw, tiles; };
struct WPack { WD d[8]; };
__global__ __launch_bounds__(256) void wprep_k(WPack p) {
    int bid = blockIdx.x;
    int mi = 0, cum = 0;
#pragma unroll
    for (mi = 0; mi < 8; ++mi) {
        if (bid < cum + p.d[mi].tiles) break;
        cum += p.d[mi].tiles;
    }
    if (mi >= 8) return;
    WD w = p.d[mi];
    int local = bid - cum;
    int tilesK = w.K >> 6;
    int tk = local % tilesK, tn = local / tilesK;
    int k0 = tk * 64, n0 = tn * 64;
    __shared__ short Tt[64 * 72];   // [n][k]
    int t = threadIdx.x;
    int row = t >> 2, seg = t & 3;
    const float* sp = w.src + (size_t)(k0 + row) * w.ldw + n0 + seg * 16;
#pragma unroll
    for (int q = 0; q < 4; ++q) {
        float4_ f = *(const float4_*)(sp + q * 4);
#pragma unroll
        for (int j = 0; j < 4; ++j) Tt[(seg * 16 + q * 4 + j) * 72 + row] = f2s(f[j]);
    }
    __syncthreads();
    bf16* dp = w.dst + (size_t)(n0 + row) * w.K + k0 + seg * 16;
    *(short8*)dp       = *(const short8*)&Tt[row * 72 + seg * 16];
    *(short8*)(dp + 8) = *(const short8*)&Tt[row * 72 + seg * 16 + 8];
}

// ---- concat q_b|k_b -> biasQK[2048] -----------------------------------------
__global__ __launch_bounds__(256) void bcat_k(const float* __restrict__ qb,
                                              const float* __restrict__ kb,
                                              float* __restrict__ dst) {
    int i = blockIdx.x * 256 + threadIdx.x;   // grid 8*256 = 2048
    dst[i] = (i < 1024) ? qb[i] : kb[i & 1023];
}

// --------- MFMA GEMM 128x128: C = A[M,K](bf16) @ WT[N,K](bf16) ---------------
// ACT: 0 none, 1 SiLU, 2 GELU(exact). res added after ACT. ldo = out/res stride.
// QKN: fused per-head RMSNorm (HD=64) on packed Q|K output; each wave's 64-col
// span is one head, so a 16-lane shuffle gives the head sum-sq. q-head norm
// weight additionally folds QSCALE so attention softmax is bare exp2.
// BROW: bias indexed by ROW (for the V^T = Wv^T @ h^T GEMM).
template <int ACT, int QKN, int BROW, typename ResT, typename OutT>
__global__ __launch_bounds__(256) void gemm_k(const bf16* __restrict__ A,
                                              const bf16* __restrict__ Bt,
                                              const float* __restrict__ bias,
                                              const ResT* __restrict__ res,
                                              OutT* __restrict__ out,
                                              int M, int N, int K, int ldo,
                                              const float* __restrict__ qn_w,
                                              const float* __restrict__ kn_w) {
    __shared__ __align__(16) short As[128 * 64];
    __shared__ __align__(16) short Bs[128 * 64];
    const int tid = threadIdx.x;
    const int bm = blockIdx.y * 128, bn = blockIdx.x * 128;
    const int wave = tid >> 6, lane = tid & 63;
    const int wm = (wave & 1) * 64, wn = (wave >> 1) * 64;
    const int l15 = lane & 15, quad = lane >> 4;
    const int lrow = lane >> 3, lseg = (lane & 7) * 8;
    float4_ acc[4][4] = {};

    for (int k0 = 0; k0 < K; k0 += 64) {
#pragma unroll
        for (int it = 0; it < 4; ++it) {
            int r = it * 32 + wave * 8;
            gl_lds16((const short*)A + (size_t)(bm + r + lrow) * K + k0 + lseg, &As[r * 64]);
            gl_lds16((const short*)Bt + (size_t)(bn + r + lrow) * K + k0 + lseg, &Bs[r * 64]);
        }
        __syncthreads();
#pragma unroll
        for (int kk = 0; kk < 64; kk += 32) {
            short8 af[4], bfr[4];
#pragma unroll
            for (int i = 0; i < 4; ++i)
                af[i] = *(const short8*)&As[(wm + i * 16 + l15) * 64 + kk + quad * 8];
#pragma unroll
            for (int j = 0; j < 4; ++j)
                bfr[j] = *(const short8*)&Bs[(wn + j * 16 + l15) * 64 + kk + quad * 8];
#pragma unroll
            for (int i = 0; i < 4; ++i)
#pragma unroll
                for (int j = 0; j < 4; ++j)
                    acc[i][j] = __builtin_amdgcn_mfma_f32_16x16x32_bf16(af[i], bfr[j], acc[i][j], 0, 0, 0);
        }
        __syncthreads();
    }

    int seg = (bn + wn) >> 10;               // QKN: 0=q, 1=k
    float nwv[4];
    if (QKN && seg < 2) {
        const float* nw = seg ? kn_w : qn_w;
        float qsc = seg ? 1.f : QSCALE;
#pragma unroll
        for (int j = 0; j < 4; ++j) nwv[j] = nw[j * 16 + l15] * qsc;
    }

#pragma unroll
    for (int i = 0; i < 4; ++i) {
        float vv[4][4];
        float bvr[4];
        if (BROW) {
#pragma unroll
            for (int r = 0; r < 4; ++r) bvr[r] = bias[bm + wm + i * 16 + quad * 4 + r];
        }
#pragma unroll
        for (int j = 0; j < 4; ++j) {
            float bv = BROW ? 0.f : bias[bn + wn + j * 16 + l15];
#pragma unroll
            for (int r = 0; r < 4; ++r) vv[j][r] = acc[i][j][r] + (BROW ? bvr[r] : bv);
        }
        if (QKN && seg < 2) {
#pragma unroll
            for (int r = 0; r < 4; ++r) {
                float ss = vv[0][r] * vv[0][r] + vv[1][r] * vv[1][r]
                         + vv[2][r] * vv[2][r] + vv[3][r] * vv[3][r];
#pragma unroll
                for (int off = 8; off > 0; off >>= 1) ss += __shfl_xor(ss, off, 16);
                float inv = rsqrtf(ss * (1.f / 64.f) + 1e-6f);
#pragma unroll
                for (int j = 0; j < 4; ++j) vv[j][r] *= inv * nwv[j];
            }
        }
#pragma unroll
        for (int j = 0; j < 4; ++j) {
            int col = bn + wn + j * 16 + l15;
#pragma unroll
            for (int r = 0; r < 4; ++r) {
                int row = bm + wm + i * 16 + quad * 4 + r;
                float v = vv[j][r];
                if (ACT == 1) v = v / (1.f + expf(-v));
                else if (ACT == 2) v = 0.5f * v * (1.f + erff(v * 0.70710678118654752f));
                if (res) v += to_f(res[(size_t)row * ldo + col]);
                store_o(&out[(size_t)row * ldo + col], v);
            }
        }
    }
}

// --------- MFMA GEMM 64x128 tile: for N=1024 GEMMs (512 blocks = 2/CU) -------
template <int ACT, typename ResT, typename OutT>
__global__ __launch_bounds__(256) void gemm64_k(const bf16* __restrict__ A,
                                                const bf16* __restrict__ Bt,
                                                const float* __restrict__ bias,
                                                const ResT* __restrict__ res,
                                                OutT* __restrict__ out,
                                                int M, int N, int K) {
    __shared__ __align__(16) short As[64 * 64];
    __shared__ __align__(16) short Bs[128 * 64];
    const int tid = threadIdx.x;
    const int bm = blockIdx.y * 64, bn = blockIdx.x * 128;
    const int wave = tid >> 6, lane = tid & 63;
    const int wm = (wave & 1) * 32, wn = (wave >> 1) * 64;
    const int l15 = lane & 15, quad = lane >> 4;
    const int lrow = lane >> 3, lseg = (lane & 7) * 8;
    float4_ acc[2][4] = {};

    for (int k0 = 0; k0 < K; k0 += 64) {
#pragma unroll
        for (int it = 0; it < 2; ++it) {
            int r = wave * 16 + it * 8;
            gl_lds16((const short*)A + (size_t)(bm + r + lrow) * K + k0 + lseg, &As[r * 64]);
        }
#pragma unroll
        for (int it = 0; it < 4; ++it) {
            int r = it * 32 + wave * 8;
            gl_lds16((const short*)Bt + (size_t)(bn + r + lrow) * K + k0 + lseg, &Bs[r * 64]);
        }
        __syncthreads();
#pragma unroll
        for (int kk = 0; kk < 64; kk += 32) {
            short8 af[2], bfr[4];
#pragma unroll
            for (int i = 0; i < 2; ++i)
                af[i] = *(const short8*)&As[(wm + i * 16 + l15) * 64 + kk + quad * 8];
#pragma unroll
            for (int j = 0; j < 4; ++j)
                bfr[j] = *(const short8*)&Bs[(wn + j * 16 + l15) * 64 + kk + quad * 8];
#pragma unroll
            for (int i = 0; i < 2; ++i)
#pragma unroll
                for (int j = 0; j < 4; ++j)
                    acc[i][j] = __builtin_amdgcn_mfma_f32_16x16x32_bf16(af[i], bfr[j], acc[i][j], 0, 0, 0);
        }
        __syncthreads();
    }

#pragma unroll
    for (int i = 0; i < 2; ++i)
#pragma unroll
        for (int j = 0; j < 4; ++j) {
            int col = bn + wn + j * 16 + l15;
            float bv = bias[col];
#pragma unroll
            for (int r = 0; r < 4; ++r) {
                int row = bm + wm + i * 16 + quad * 4 + r;
                float v = acc[i][j][r] + bv;
                if (ACT == 1) v = v / (1.f + expf(-v));
                else if (ACT == 2) v = 0.5f * v * (1.f + erff(v * 0.70710678118654752f));
                if (res) v += to_f(res[(size_t)row * N + col]);
                store_o(&out[(size_t)row * N + col], v);
            }
        }
}

// -------------- flash attention, causal, HD=64, q-tile 64, KV tile 64 --------
// R1 pipelined skeleton + two fixes:
//  * V arrives PRE-TRANSPOSED (VT GEMM output [1024 hd][4096 tok]) and is
//    staged via global_load_lds (zero VALU, no scalar transpose writes).
//  * XOR-swizzled staging: global source block pre-swizzled per lane
//    (blk ^ row&7), linear LDS dest; ds_read applies the same XOR ->
//    conflict-free b128 reads (was a 4-way write conflict = 9.2M cycles).
// K fragments direct from global (L1-served, proven in R1). NO-MAX softmax
// (qk-RMSNorm bounds |s|), Q pre-scaled by 0.125*log2e -> bare exp2.
// Partial (O,l) combine linearly across KV chunks (nc = qb/8+1).
static __device__ __forceinline__ int chunk_base(int qb) {  // first slot, qb>=8
    return (qb < 16) ? (qb - 8) * 2
         : (qb < 24) ? 16 + (qb - 16) * 3
                     : 40 + (qb - 24) * 4;
}

template <int SPLIT>
__global__ __launch_bounds__(256) void attn_k(const bf16* __restrict__ QK,  // [NTOK][2048] q|k
                                              const bf16* __restrict__ VT,  // [1024][4096]
                                              bf16* __restrict__ O,
                                              float* __restrict__ OP,
                                              float* __restrict__ LP) {
    __shared__ __align__(16) short Vs[2][64 * 64];  // [hd][kv], XOR-swizzled blocks
    __shared__ __align__(16) short Ps[4][16 * 72];  // per-wave [q][kv]
    const int bh = blockIdx.y, b = bh >> 4, h = bh & 15;
    int qb, ci;
    if (SPLIT) {
        int idx = 79 - (int)blockIdx.x;             // big chunks dispatch first
        if (idx < 8)       { qb = idx; ci = 0; }
        else if (idx < 24) { qb = 8 + ((idx - 8) >> 1); ci = (idx - 8) & 1; }
        else if (idx < 48) { int u = idx - 24; int q3 = u / 3; qb = 16 + q3; ci = u - q3 * 3; }
        else               { int u = idx - 48; qb = 24 + (u >> 2); ci = u & 3; }
    } else { qb = 31 - (int)blockIdx.x; ci = 0; }
    const int n   = qb + 1;                          // causal KV tiles for qb
    const int nc  = SPLIT ? ((qb >> 3) + 1) : 1;
    const int bsz = n / nc, rem = n - bsz * nc;      // balanced chunk sizes
    const int t0  = ci * bsz + (ci < rem ? ci : rem);
    const int t1  = t0 + bsz + (ci < rem ? 1 : 0);
    const int q0  = qb * 64;
    const int tid = threadIdx.x, wave = tid >> 6, lane = tid & 63;
    const int l15 = lane & 15, quad = lane >> 4;

    const short* Qp  = (const short*)QK + (size_t)b * T_ * 2048 + h * 64;
    const short* Kp  = Qp + 1024;
    const short* Vtp = (const short*)VT + (size_t)h * 64 * 4096 + b * T_;

    const int qrow = q0 + wave * 16 + l15;
    short8 qf0 = *(const short8*)(Qp + (size_t)qrow * 2048 + quad * 8);
    short8 qf1 = *(const short8*)(Qp + (size_t)qrow * 2048 + 32 + quad * 8);

    float4_ oacc[4] = {};
    float l_r[4] = {0.f, 0.f, 0.f, 0.f};

    const int slr  = lane >> 3;                      // row within 8-row group
    const int sblk = (lane & 7) ^ slr;               // pre-swizzled source block

    {   // stage V tile t0 into buf 0 (global_load_lds, swizzled source)
#pragma unroll
        for (int it = 0; it < 2; ++it) {
            int r = it * 32 + wave * 8;
            gl_lds16(Vtp + (size_t)(r + slr) * 4096 + t0 * 64 + sblk * 8, &Vs[0][r * 64]);
        }
    }
    __syncthreads();

    for (int t = t0; t < t1; ++t) {
        const int kv0 = t * 64, buf = (t - t0) & 1;
        if (t + 1 < t1) {   // prefetch next V tile into other buffer
#pragma unroll
            for (int it = 0; it < 2; ++it) {
                int r = it * 32 + wave * 8;
                gl_lds16(Vtp + (size_t)(r + slr) * 4096 + kv0 + 64 + sblk * 8, &Vs[buf ^ 1][r * 64]);
            }
        }

        // QK^T: K fragments direct from global (coalesced 16B/lane)
        float4_ s[4];
#pragma unroll
        for (int c = 0; c < 4; ++c) {
            const short* kp = Kp + (size_t)(kv0 + c * 16 + l15) * 2048 + quad * 8;
            short8 kb0 = *(const short8*)kp;
            short8 kb1 = *(const short8*)(kp + 32);
            float4_ sc = {};
            sc = __builtin_amdgcn_mfma_f32_16x16x32_bf16(qf0, kb0, sc, 0, 0, 0);
            sc = __builtin_amdgcn_mfma_f32_16x16x32_bf16(qf1, kb1, sc, 0, 0, 0);
            s[c] = sc;
        }

        // exp2 + per-lane l accumulate; causal mask only on the diagonal tile
        if (t == qb) {
#pragma unroll
            for (int r = 0; r < 4; ++r) {
                int qr = q0 + wave * 16 + quad * 4 + r;
#pragma unroll
                for (int c = 0; c < 4; ++c) {
                    int kvi = kv0 + c * 16 + l15;
                    float p = __builtin_amdgcn_exp2f(s[c][r]);
                    p = (kvi > qr) ? 0.f : p;
                    s[c][r] = p;
                    l_r[r] += p;
                }
            }
        } else {
#pragma unroll
            for (int r = 0; r < 4; ++r)
#pragma unroll
                for (int c = 0; c < 4; ++c) {
                    float p = __builtin_amdgcn_exp2f(s[c][r]);
                    s[c][r] = p;
                    l_r[r] += p;
                }
        }

        // P: C/D -> A layout via per-wave LDS (wave-synchronous, no barrier)
#pragma unroll
        for (int c = 0; c < 4; ++c) {
            int pk01, pk23;
            asm("v_cvt_pk_bf16_f32 %0, %1, %2" : "=v"(pk01) : "v"(s[c][0]), "v"(s[c][1]));
            asm("v_cvt_pk_bf16_f32 %0, %1, %2" : "=v"(pk23) : "v"(s[c][2]), "v"(s[c][3]));
            short* pp = &Ps[wave][(quad * 4) * 72 + c * 16 + l15];
            pp[0]   = (short)pk01;
            pp[72]  = (short)(((unsigned)pk01) >> 16);
            pp[144] = (short)pk23;
            pp[216] = (short)(((unsigned)pk23) >> 16);
        }

        const int vkey = (l15 & 7) * 8;              // read-side XOR (shorts)
#pragma unroll
        for (int kk = 0; kk < 64; kk += 32) {
            short8 pf = *(const short8*)&Ps[wave][l15 * 72 + kk + quad * 8];
#pragma unroll
            for (int d = 0; d < 4; ++d) {
                short8 vf = *(const short8*)&Vs[buf][(d * 16 + l15) * 64 + ((kk + quad * 8) ^ vkey)];
                oacc[d] = __builtin_amdgcn_mfma_f32_16x16x32_bf16(pf, vf, oacc[d], 0, 0, 0);
            }
        }
        __syncthreads();   // single barrier per KV tile (drains gl_lds too)
    }

    // deferred l reduction: sum over the 16-lane group (one row each)
    float lsum[4];
#pragma unroll
    for (int r = 0; r < 4; ++r) {
        float l = l_r[r];
#pragma unroll
        for (int off = 8; off > 0; off >>= 1) l += __shfl_xor(l, off, 16);
        lsum[r] = l;
    }

    if (!SPLIT || nc == 1) {
        // single chunk: normalize and write final bf16 O
#pragma unroll
        for (int d = 0; d < 4; ++d)
#pragma unroll
            for (int r = 0; r < 4; ++r) {
                int qr = q0 + wave * 16 + quad * 4 + r;
                O[(size_t)(b * T_ + qr) * D_ + h * 64 + d * 16 + l15] = f2b(oacc[d][r] / lsum[r]);
            }
    } else {
        // chunked: emit unnormalized fp32 partial + l
        const int slot = bh * 72 + chunk_base(qb) + ci;
        float* op = OP + (size_t)slot * 4096;
#pragma unroll
        for (int d = 0; d < 4; ++d)
#pragma unroll
            for (int r = 0; r < 4; ++r)
                op[(wave * 16 + quad * 4 + r) * 64 + d * 16 + l15] = oacc[d][r];
        if (l15 == 0) {
#pragma unroll
            for (int r = 0; r < 4; ++r)
                LP[slot * 64 + wave * 16 + quad * 4 + r] = lsum[r];
        }
    }
}

// --- combine KV-chunk partials: O = (sum_c O_c) / (sum_c l_c), bf16 out ------
__global__ __launch_bounds__(256) void comb_k(const float* __restrict__ OP,
                                              const float* __restrict__ LP,
                                              bf16* __restrict__ O) {
    const int qb = 8 + (int)blockIdx.x;              // only qb>=8 were chunked
    const int bh = blockIdx.y, b = bh >> 4, h = bh & 15;
    const int nc = (qb >> 3) + 1;                    // 2..4 chunks
    const int slot0 = bh * 72 + chunk_base(qb);
    const int tid = threadIdx.x;
    const int row = tid >> 2, c0 = (tid & 3) << 4;   // 16 floats per thread
    const float* p = OP + (size_t)slot0 * 4096 + row * 64 + c0;
    float4_ a0 = *(const float4_*)(p + 0);
    float4_ a1 = *(const float4_*)(p + 4);
    float4_ a2 = *(const float4_*)(p + 8);
    float4_ a3 = *(const float4_*)(p + 12);
    float l = LP[slot0 * 64 + row];
    for (int c = 1; c < nc; ++c) {
        const float* q = p + (size_t)c * 4096;
        a0 += *(const float4_*)(q + 0);
        a1 += *(const float4_*)(q + 4);
        a2 += *(const float4_*)(q + 8);
        a3 += *(const float4_*)(q + 12);
        l += LP[(slot0 + c) * 64 + row];
    }
    float inv = 1.f / l;
    short8 w0, w1;
#pragma unroll
    for (int j = 0; j < 4; ++j) {
        w0[j]     = f2s(a0[j] * inv);
        w0[4 + j] = f2s(a1[j] * inv);
        w1[j]     = f2s(a2[j] * inv);
        w1[4 + j] = f2s(a3[j] * inv);
    }
    bf16* o = O + (size_t)(b * T_ + qb * 64 + row) * D_ + h * 64 + c0;
    *(short8*)o       = w0;
    *(short8*)(o + 8) = w1;
}

// ---------------------------------------------------------------------------
// Workspace:
//   Ah[0,8) ; QKp[8,24) ([NTOK][2048] bf16 q|k) ; VT4[24,32) ([1024][4096]) ;
//   AO[32,40) ; after attn+o-proj: AE1[8,16) AES[16,24) MOD[24,40) ;
//   M1G[8,40) after modnorm.
//   weights [40,70): WTqkv 40 WTo 46 WTae2 48 WTmod 50 WTm1 54 WTm2 62
//   biasQK at 70MB; OPART at 70MB+16K (2304*16KB); LPART after (576KB).
//   X1 (fp32 residual) lives in d_out.
extern "C" void kernel_launch(void* const* d_in, const int* in_sizes, int n_in,
                              void* d_out, int out_size, void* d_ws, size_t ws_size,
                              hipStream_t stream) {
    const float* x     = (const float*)d_in[0];
    const float* acts  = (const float*)d_in[1];
    const float* n1_w  = (const float*)d_in[2];
    const float* n2_w  = (const float*)d_in[3];
    const float* q_w   = (const float*)d_in[4];
    const float* q_b   = (const float*)d_in[5];
    const float* k_w   = (const float*)d_in[6];
    const float* k_b   = (const float*)d_in[7];
    const float* v_w   = (const float*)d_in[8];
    const float* v_b   = (const float*)d_in[9];
    const float* qn_w  = (const float*)d_in[10];
    const float* kn_w  = (const float*)d_in[11];
    const float* o_w   = (const float*)d_in[12];
    const float* o_b   = (const float*)d_in[13];
    const float* ae1_w = (const float*)d_in[14];
    const float* ae1_b = (const float*)d_in[15];
    const float* ae2_w = (const float*)d_in[16];
    const float* ae2_b = (const float*)d_in[17];
    const float* mod_w = (const float*)d_in[18];
    const float* mod_b = (const float*)d_in[19];
    const float* m1_w  = (const float*)d_in[20];
    const float* m1_b  = (const float*)d_in[21];
    const float* m2_w  = (const float*)d_in[22];
    const float* m2_b  = (const float*)d_in[23];
    float* out = (float*)d_out;

    char* ws = (char*)d_ws;
    const size_t MB = 1ull << 20;
    bf16*  Ah   = (bf16*)(ws + 0);
    bf16*  QKp  = (bf16*)(ws + 8 * MB);    // [NTOK][2048]
    bf16*  VT4  = (bf16*)(ws + 24 * MB);   // [1024][4096]
    bf16*  AO   = (bf16*)(ws + 32 * MB);
    bf16*  AE1  = (bf16*)(ws + 8 * MB);
    bf16*  AES  = (bf16*)(ws + 16 * MB);
    bf16*  MOD  = (bf16*)(ws + 24 * MB);
    bf16*  M1G  = (bf16*)(ws + 8 * MB);
    float* X1   = out;

    bf16* WTqkv = (bf16*)(ws + 40 * MB);   // q|k|v contiguous -> [3072][1024]
    bf16* WTv   = WTqkv + 2048 * 1024;
    bf16* WTo   = (bf16*)(ws + 46 * MB);
    bf16* WTae2 = (bf16*)(ws + 48 * MB);
    bf16* WTmod = (bf16*)(ws + 50 * MB);   // [2048][1024]
    bf16* WTm1  = (bf16*)(ws + 54 * MB);   // [4096][1024]
    bf16* WTm2  = (bf16*)(ws + 62 * MB);   // [1024][4096]
    float* biasQK = (float*)(ws + 70 * MB);
    float* OPART  = (float*)(ws + 70 * MB + 16384);            // 2304 * 16 KB
    float* LPART  = (float*)(ws + 70 * MB + 16384 + 37748736); // 2304 * 256 B
    const bool split = ws_size >= (70 * MB + 16384 + 37748736ull + 589824ull);

    dim3 blk(256);

    WPack p;
    p.d[0] = { q_w,   WTqkv,                1024, 1024, 1024, 256 };
    p.d[1] = { k_w,   WTqkv + 1024 * 1024,  1024, 1024, 1024, 256 };
    p.d[2] = { v_w,   WTqkv + 2048 * 1024,  1024, 1024, 1024, 256 };
    p.d[3] = { o_w,   WTo,   1024, 1024, 1024, 256 };
    p.d[4] = { ae2_w, WTae2, 1024, 1024, 1024, 256 };
    p.d[5] = { mod_w, WTmod, 1024, 2048, 4096, 512 };
    p.d[6] = { m1_w,  WTm1,  1024, 4096, 4096, 1024 };
    p.d[7] = { m2_w,  WTm2,  4096, 1024, 1024, 1024 };
    wprep_k<<<3840, blk, 0, stream>>>(p);
    bcat_k<<<8, blk, 0, stream>>>(q_b, k_b, biasQK);

    rmsnorm_k<<<NTOK, blk, 0, stream>>>(x, n1_w, Ah);
    // Q|K projection + fused per-head RMSNorm (q side folds QSCALE)
    gemm_k<0, 1, 0, float, bf16><<<dim3(16, 32), blk, 0, stream>>>(Ah, WTqkv, biasQK, (const float*)nullptr, QKp, NTOK, 2048, 1024, 2048, qn_w, kn_w);
    // V^T = WTv @ Ah^T : [1024 v-cols][4096 tokens], bias per row
    gemm_k<0, 0, 1, float, bf16><<<dim3(32, 8), blk, 0, stream>>>(WTv, Ah, v_b, (const float*)nullptr, VT4, 1024, 4096, 1024, 4096, nullptr, nullptr);
    if (split) {
        attn_k<1><<<dim3(80, B_ * H_), blk, 0, stream>>>(QKp, VT4, AO, OPART, LPART);
        comb_k<<<dim3(24, B_ * H_), blk, 0, stream>>>(OPART, LPART, AO);
    } else {
        attn_k<0><<<dim3(32, B_ * H_), blk, 0, stream>>>(QKp, VT4, AO, OPART, LPART);
    }
    gemm64_k<0, float, float><<<dim3(8, 64), blk, 0, stream>>>(AO, WTo, o_b, x, X1, NTOK, 1024, 1024);
    ae1_k<<<NTOK, blk, 0, stream>>>(acts, ae1_w, ae1_b, AE1);
    gemm64_k<1, float, bf16><<<dim3(8, 64), blk, 0, stream>>>(AE1, WTae2, ae2_b, (const float*)nullptr, AES, NTOK, 1024, 1024);
    gemm_k<0, 0, 0, float, bf16><<<dim3(16, 32), blk, 0, stream>>>(AES, WTmod, mod_b, (const float*)nullptr, MOD, NTOK, 2048, 1024, 2048, nullptr, nullptr);
    modnorm_k<<<NTOK, blk, 0, stream>>>(X1, MOD, n2_w, Ah);
    gemm_k<2, 0, 0, float, bf16><<<dim3(32, 32), blk, 0, stream>>>(Ah, WTm1, m1_b, (const float*)nullptr, M1G, NTOK, 4096, 1024, 4096, nullptr, nullptr);
    gemm64_k<0, float, float><<<dim3(8, 64), blk, 0, stream>>>(M1G, WTm2, m2_b, X1, out, NTOK, 1024, 4096);
}

// Round 4
// 523.696 us; speedup vs baseline: 1.1827x; 1.0778x over previous
//
#include <hip/hip_runtime.h>
#include <hip/hip_bf16.h>
#include <math.h>

typedef __hip_bfloat16 bf16;
typedef __attribute__((ext_vector_type(8))) short short8;
typedef __attribute__((ext_vector_type(4))) float float4_;

#define B_   2
#define T_   2048
#define D_   1024
#define H_   16
#define NTOK (B_ * T_)
// 0.125 * log2(e): folded into q-side RMSNorm weight so attn uses raw exp2.
#define QSCALE 0.18033688011112042f

#define AS1 __attribute__((address_space(1)))
#define AS3 __attribute__((address_space(3)))

static __device__ __forceinline__ float b2f(bf16 v) { return __bfloat162float(v); }
static __device__ __forceinline__ bf16  f2b(float v) { return __float2bfloat16(v); }
static __device__ __forceinline__ short f2s(float v) {  // fp32 -> bf16 bits (RNE)
    unsigned u = __builtin_bit_cast(unsigned, v);
    unsigned r = (u + 0x7FFFu + ((u >> 16) & 1u)) >> 16;
    return (short)r;
}
static __device__ __forceinline__ float to_f(float v) { return v; }
static __device__ __forceinline__ float to_f(bf16 v) { return __bfloat162float(v); }
static __device__ __forceinline__ void  store_o(float* p, float v) { *p = v; }
static __device__ __forceinline__ void  store_o(bf16* p, float v) { *p = __float2bfloat16(v); }
static __device__ __forceinline__ void gl_lds16(const void* g, void* l) {
    __builtin_amdgcn_global_load_lds((const AS1 unsigned int*)g, (AS3 unsigned int*)l, 16, 0, 0);
}

// ---------------- RMSNorm over D=1024 (one block per token), fp32 in, bf16 out
__global__ __launch_bounds__(256) void rmsnorm_k(const float* __restrict__ x,
                                                 const float* __restrict__ w,
                                                 bf16* __restrict__ out) {
    int t = blockIdx.x, tid = threadIdx.x;
    float xs[4], ss = 0.f;
#pragma unroll
    for (int i = 0; i < 4; ++i) {
        float v = x[(size_t)t * D_ + tid + i * 256];
        xs[i] = v; ss += v * v;
    }
    __shared__ float red[4];
#pragma unroll
    for (int off = 32; off > 0; off >>= 1) ss += __shfl_xor(ss, off, 64);
    if ((tid & 63) == 0) red[tid >> 6] = ss;
    __syncthreads();
    ss = red[0] + red[1] + red[2] + red[3];
    float inv = rsqrtf(ss * (1.f / D_) + 1e-6f);
#pragma unroll
    for (int i = 0; i < 4; ++i) {
        int c = tid + i * 256;
        out[(size_t)t * D_ + c] = f2b(xs[i] * inv * w[c]);
    }
}

// ------- fused modulate (x = x*(1+scale1)+shift1, in place fp32) + RMSNorm2 --
__global__ __launch_bounds__(256) void modnorm_k(float* __restrict__ x1,
                                                 const bf16* __restrict__ mod, // [NTOK][2048] = shift|scale
                                                 const float* __restrict__ w,
                                                 bf16* __restrict__ h2) {
    int t = blockIdx.x, tid = threadIdx.x;
    float xs[4], ss = 0.f;
#pragma unroll
    for (int i = 0; i < 4; ++i) {
        int c = tid + i * 256;
        float sh = b2f(mod[(size_t)t * 2048 + c]);
        float sc = b2f(mod[(size_t)t * 2048 + 1024 + c]);
        float v = x1[(size_t)t * D_ + c] * (1.f + sc) + sh;
        xs[i] = v; ss += v * v;
        x1[(size_t)t * D_ + c] = v;
    }
    __shared__ float red[4];
#pragma unroll
    for (int off = 32; off > 0; off >>= 1) ss += __shfl_xor(ss, off, 64);
    if ((tid & 63) == 0) red[tid >> 6] = ss;
    __syncthreads();
    ss = red[0] + red[1] + red[2] + red[3];
    float inv = rsqrtf(ss * (1.f / D_) + 1e-6f);
#pragma unroll
    for (int i = 0; i < 4; ++i) {
        int c = tid + i * 256;
        h2[(size_t)t * D_ + c] = f2b(xs[i] * inv * w[c]);
    }
}

// ------------- ae1: [NTOK,16] @ [16,1024] + b, SiLU (fp32 in, bf16 out) -----
__global__ __launch_bounds__(256) void ae1_k(const float* __restrict__ actions,
                                             const float* __restrict__ w,
                                             const float* __restrict__ b,
                                             bf16* __restrict__ out) {
    int t = blockIdx.x, tid = threadIdx.x;
    float av[16];
#pragma unroll
    for (int a = 0; a < 16; ++a) av[a] = actions[(size_t)t * 16 + a];
#pragma unroll
    for (int i = 0; i < 4; ++i) {
        int n = tid + i * 256;
        float acc = b[n];
#pragma unroll
        for (int a = 0; a < 16; ++a) acc += av[a] * w[a * D_ + n];
        out[(size_t)t * D_ + n] = f2b(acc / (1.f + expf(-acc)));
    }
}

// ---- weight prep: fp32 W[K][N] (row stride ldw) -> bf16 WT[N][K], fused -----
struct WD { const float* src; bf16* dst; int K, N, ldw, tiles; };
struct WPack { WD d[8]; };
__global__ __launch_bounds__(256) void wprep_k(WPack p) {
    int bid = blockIdx.x;
    int mi = 0, cum = 0;
#pragma unroll
    for (mi = 0; mi < 8; ++mi) {
        if (bid < cum + p.d[mi].tiles) break;
        cum += p.d[mi].tiles;
    }
    if (mi >= 8) return;
    WD w = p.d[mi];
    int local = bid - cum;
    int tilesK = w.K >> 6;
    int tk = local % tilesK, tn = local / tilesK;
    int k0 = tk * 64, n0 = tn * 64;
    __shared__ short Tt[64 * 72];   // [n][k]
    int t = threadIdx.x;
    int row = t >> 2, seg = t & 3;
    const float* sp = w.src + (size_t)(k0 + row) * w.ldw + n0 + seg * 16;
#pragma unroll
    for (int q = 0; q < 4; ++q) {
        float4_ f = *(const float4_*)(sp + q * 4);
#pragma unroll
        for (int j = 0; j < 4; ++j) Tt[(seg * 16 + q * 4 + j) * 72 + row] = f2s(f[j]);
    }
    __syncthreads();
    bf16* dp = w.dst + (size_t)(n0 + row) * w.K + k0 + seg * 16;
    *(short8*)dp       = *(const short8*)&Tt[row * 72 + seg * 16];
    *(short8*)(dp + 8) = *(const short8*)&Tt[row * 72 + seg * 16 + 8];
}

// ---- concat q_b|k_b -> biasQK[2048] -----------------------------------------
__global__ __launch_bounds__(256) void bcat_k(const float* __restrict__ qb,
                                              const float* __restrict__ kb,
                                              float* __restrict__ dst) {
    int i = blockIdx.x * 256 + threadIdx.x;   // grid 8*256 = 2048
    dst[i] = (i < 1024) ? qb[i] : kb[i & 1023];
}

// --------- MFMA GEMM 128x128: C = A[M,K](bf16) @ WT[N,K](bf16) ---------------
// ACT: 0 none, 1 SiLU, 2 GELU(exact). res added after ACT. ldo = out/res stride.
// QKN: fused per-head RMSNorm (HD=64) on packed Q|K output; each wave's 64-col
// span is one head, so a 16-lane shuffle gives the head sum-sq. q-head norm
// weight additionally folds QSCALE so attention softmax is bare exp2.
// BROW: bias indexed by ROW (for the V^T = Wv^T @ h^T GEMM).
template <int ACT, int QKN, int BROW, typename ResT, typename OutT>
__global__ __launch_bounds__(256) void gemm_k(const bf16* __restrict__ A,
                                              const bf16* __restrict__ Bt,
                                              const float* __restrict__ bias,
                                              const ResT* __restrict__ res,
                                              OutT* __restrict__ out,
                                              int M, int N, int K, int ldo,
                                              const float* __restrict__ qn_w,
                                              const float* __restrict__ kn_w) {
    __shared__ __align__(16) short As[128 * 64];
    __shared__ __align__(16) short Bs[128 * 64];
    const int tid = threadIdx.x;
    const int bm = blockIdx.y * 128, bn = blockIdx.x * 128;
    const int wave = tid >> 6, lane = tid & 63;
    const int wm = (wave & 1) * 64, wn = (wave >> 1) * 64;
    const int l15 = lane & 15, quad = lane >> 4;
    const int lrow = lane >> 3, lseg = (lane & 7) * 8;
    float4_ acc[4][4] = {};

    for (int k0 = 0; k0 < K; k0 += 64) {
#pragma unroll
        for (int it = 0; it < 4; ++it) {
            int r = it * 32 + wave * 8;
            gl_lds16((const short*)A + (size_t)(bm + r + lrow) * K + k0 + lseg, &As[r * 64]);
            gl_lds16((const short*)Bt + (size_t)(bn + r + lrow) * K + k0 + lseg, &Bs[r * 64]);
        }
        __syncthreads();
#pragma unroll
        for (int kk = 0; kk < 64; kk += 32) {
            short8 af[4], bfr[4];
#pragma unroll
            for (int i = 0; i < 4; ++i)
                af[i] = *(const short8*)&As[(wm + i * 16 + l15) * 64 + kk + quad * 8];
#pragma unroll
            for (int j = 0; j < 4; ++j)
                bfr[j] = *(const short8*)&Bs[(wn + j * 16 + l15) * 64 + kk + quad * 8];
#pragma unroll
            for (int i = 0; i < 4; ++i)
#pragma unroll
                for (int j = 0; j < 4; ++j)
                    acc[i][j] = __builtin_amdgcn_mfma_f32_16x16x32_bf16(af[i], bfr[j], acc[i][j], 0, 0, 0);
        }
        __syncthreads();
    }

    int seg = (bn + wn) >> 10;               // QKN: 0=q, 1=k
    float nwv[4];
    if (QKN && seg < 2) {
        const float* nw = seg ? kn_w : qn_w;
        float qsc = seg ? 1.f : QSCALE;
#pragma unroll
        for (int j = 0; j < 4; ++j) nwv[j] = nw[j * 16 + l15] * qsc;
    }

#pragma unroll
    for (int i = 0; i < 4; ++i) {
        float vv[4][4];
        float bvr[4];
        if (BROW) {
#pragma unroll
            for (int r = 0; r < 4; ++r) bvr[r] = bias[bm + wm + i * 16 + quad * 4 + r];
        }
#pragma unroll
        for (int j = 0; j < 4; ++j) {
            float bv = BROW ? 0.f : bias[bn + wn + j * 16 + l15];
#pragma unroll
            for (int r = 0; r < 4; ++r) vv[j][r] = acc[i][j][r] + (BROW ? bvr[r] : bv);
        }
        if (QKN && seg < 2) {
#pragma unroll
            for (int r = 0; r < 4; ++r) {
                float ss = vv[0][r] * vv[0][r] + vv[1][r] * vv[1][r]
                         + vv[2][r] * vv[2][r] + vv[3][r] * vv[3][r];
#pragma unroll
                for (int off = 8; off > 0; off >>= 1) ss += __shfl_xor(ss, off, 16);
                float inv = rsqrtf(ss * (1.f / 64.f) + 1e-6f);
#pragma unroll
                for (int j = 0; j < 4; ++j) vv[j][r] *= inv * nwv[j];
            }
        }
#pragma unroll
        for (int j = 0; j < 4; ++j) {
            int col = bn + wn + j * 16 + l15;
#pragma unroll
            for (int r = 0; r < 4; ++r) {
                int row = bm + wm + i * 16 + quad * 4 + r;
                float v = vv[j][r];
                if (ACT == 1) v = v / (1.f + expf(-v));
                else if (ACT == 2) v = 0.5f * v * (1.f + erff(v * 0.70710678118654752f));
                if (res) v += to_f(res[(size_t)row * ldo + col]);
                store_o(&out[(size_t)row * ldo + col], v);
            }
        }
    }
}

// --------- MFMA GEMM 64x128 tile: for N=1024 GEMMs (512 blocks = 2/CU) -------
template <int ACT, typename ResT, typename OutT>
__global__ __launch_bounds__(256) void gemm64_k(const bf16* __restrict__ A,
                                                const bf16* __restrict__ Bt,
                                                const float* __restrict__ bias,
                                                const ResT* __restrict__ res,
                                                OutT* __restrict__ out,
                                                int M, int N, int K) {
    __shared__ __align__(16) short As[64 * 64];
    __shared__ __align__(16) short Bs[128 * 64];
    const int tid = threadIdx.x;
    const int bm = blockIdx.y * 64, bn = blockIdx.x * 128;
    const int wave = tid >> 6, lane = tid & 63;
    const int wm = (wave & 1) * 32, wn = (wave >> 1) * 64;
    const int l15 = lane & 15, quad = lane >> 4;
    const int lrow = lane >> 3, lseg = (lane & 7) * 8;
    float4_ acc[2][4] = {};

    for (int k0 = 0; k0 < K; k0 += 64) {
#pragma unroll
        for (int it = 0; it < 2; ++it) {
            int r = wave * 16 + it * 8;
            gl_lds16((const short*)A + (size_t)(bm + r + lrow) * K + k0 + lseg, &As[r * 64]);
        }
#pragma unroll
        for (int it = 0; it < 4; ++it) {
            int r = it * 32 + wave * 8;
            gl_lds16((const short*)Bt + (size_t)(bn + r + lrow) * K + k0 + lseg, &Bs[r * 64]);
        }
        __syncthreads();
#pragma unroll
        for (int kk = 0; kk < 64; kk += 32) {
            short8 af[2], bfr[4];
#pragma unroll
            for (int i = 0; i < 2; ++i)
                af[i] = *(const short8*)&As[(wm + i * 16 + l15) * 64 + kk + quad * 8];
#pragma unroll
            for (int j = 0; j < 4; ++j)
                bfr[j] = *(const short8*)&Bs[(wn + j * 16 + l15) * 64 + kk + quad * 8];
#pragma unroll
            for (int i = 0; i < 2; ++i)
#pragma unroll
                for (int j = 0; j < 4; ++j)
                    acc[i][j] = __builtin_amdgcn_mfma_f32_16x16x32_bf16(af[i], bfr[j], acc[i][j], 0, 0, 0);
        }
        __syncthreads();
    }

#pragma unroll
    for (int i = 0; i < 2; ++i)
#pragma unroll
        for (int j = 0; j < 4; ++j) {
            int col = bn + wn + j * 16 + l15;
            float bv = bias[col];
#pragma unroll
            for (int r = 0; r < 4; ++r) {
                int row = bm + wm + i * 16 + quad * 4 + r;
                float v = acc[i][j][r] + bv;
                if (ACT == 1) v = v / (1.f + expf(-v));
                else if (ACT == 2) v = 0.5f * v * (1.f + erff(v * 0.70710678118654752f));
                if (res) v += to_f(res[(size_t)row * N + col]);
                store_o(&out[(size_t)row * N + col], v);
            }
        }
}

// -------------- flash attention, causal, HD=64, q-tile 64, KV tile 64 --------
// R3 skeleton with BOTH K and V staged through LDS via global_load_lds
// (double-buffered, prefetched one tile ahead). The per-tile blocking wait on
// 8 global K-fragment loads -- the R3 critical path -- is gone; K VMEM traffic
// drops 4x (8KB staged once per block vs per-wave redundant loads). Same
// source-swizzle / read-XOR pair as V (16 l15-lanes x 128B-stride rows would
// be a 16-way conflict linear; XOR spreads across 8 banksets, 2-way = free).
// NO-MAX softmax (qk-RMSNorm bounds |s|), Q pre-scaled by 0.125*log2e -> bare
// exp2. Partial (O,l) combine linearly across KV chunks (nc = qb/8+1).
static __device__ __forceinline__ int chunk_base(int qb) {  // first slot, qb>=8
    return (qb < 16) ? (qb - 8) * 2
         : (qb < 24) ? 16 + (qb - 16) * 3
                     : 40 + (qb - 24) * 4;
}

template <int SPLIT>
__global__ __launch_bounds__(256) void attn_k(const bf16* __restrict__ QK,  // [NTOK][2048] q|k
                                              const bf16* __restrict__ VT,  // [1024][4096]
                                              bf16* __restrict__ O,
                                              float* __restrict__ OP,
                                              float* __restrict__ LP) {
    __shared__ __align__(16) short Ks[2][64 * 64];  // [kv][hd], XOR-swizzled blocks
    __shared__ __align__(16) short Vs[2][64 * 64];  // [hd][kv], XOR-swizzled blocks
    __shared__ __align__(16) short Ps[4][16 * 72];  // per-wave [q][kv]
    const int bh = blockIdx.y, b = bh >> 4, h = bh & 15;
    int qb, ci;
    if (SPLIT) {
        int idx = 79 - (int)blockIdx.x;             // big chunks dispatch first
        if (idx < 8)       { qb = idx; ci = 0; }
        else if (idx < 24) { qb = 8 + ((idx - 8) >> 1); ci = (idx - 8) & 1; }
        else if (idx < 48) { int u = idx - 24; int q3 = u / 3; qb = 16 + q3; ci = u - q3 * 3; }
        else               { int u = idx - 48; qb = 24 + (u >> 2); ci = u & 3; }
    } else { qb = 31 - (int)blockIdx.x; ci = 0; }
    const int n   = qb + 1;                          // causal KV tiles for qb
    const int nc  = SPLIT ? ((qb >> 3) + 1) : 1;
    const int bsz = n / nc, rem = n - bsz * nc;      // balanced chunk sizes
    const int t0  = ci * bsz + (ci < rem ? ci : rem);
    const int t1  = t0 + bsz + (ci < rem ? 1 : 0);
    const int q0  = qb * 64;
    const int tid = threadIdx.x, wave = tid >> 6, lane = tid & 63;
    const int l15 = lane & 15, quad = lane >> 4;

    const short* Qp  = (const short*)QK + (size_t)b * T_ * 2048 + h * 64;
    const short* Kp  = Qp + 1024;
    const short* Vtp = (const short*)VT + (size_t)h * 64 * 4096 + b * T_;

    const int qrow = q0 + wave * 16 + l15;
    short8 qf0 = *(const short8*)(Qp + (size_t)qrow * 2048 + quad * 8);
    short8 qf1 = *(const short8*)(Qp + (size_t)qrow * 2048 + 32 + quad * 8);

    float4_ oacc[4] = {};
    float l_r[4] = {0.f, 0.f, 0.f, 0.f};

    const int slr  = lane >> 3;                      // row within 8-row group
    const int sblk = (lane & 7) ^ slr;               // pre-swizzled source block

    // stage K+V tile t into buffer bb (global_load_lds, swizzled source)
#define STAGE_KV(t, bb)                                                          \
    {                                                                            \
        _Pragma("unroll")                                                        \
        for (int it = 0; it < 2; ++it) {                                         \
            int r = it * 32 + wave * 8;                                          \
            gl_lds16(Kp + (size_t)((t) * 64 + r + slr) * 2048 + sblk * 8, &Ks[bb][r * 64]); \
            gl_lds16(Vtp + (size_t)(r + slr) * 4096 + (t) * 64 + sblk * 8, &Vs[bb][r * 64]); \
        }                                                                        \
    }

    STAGE_KV(t0, 0);
    __syncthreads();

    const int xkey = (l15 & 7) * 8;                  // read-side XOR (shorts)

    for (int t = t0; t < t1; ++t) {
        const int kv0 = t * 64, buf = (t - t0) & 1;
        if (t + 1 < t1) STAGE_KV(t + 1, buf ^ 1);    // prefetch next tile

        // QK^T: K fragments from LDS (swizzled, conflict-free)
        float4_ s[4];
#pragma unroll
        for (int c = 0; c < 4; ++c) {
            const short* kr = &Ks[buf][(c * 16 + l15) * 64];
            short8 kb0 = *(const short8*)&kr[(quad * 8) ^ xkey];
            short8 kb1 = *(const short8*)&kr[(32 + quad * 8) ^ xkey];
            float4_ sc = {};
            sc = __builtin_amdgcn_mfma_f32_16x16x32_bf16(qf0, kb0, sc, 0, 0, 0);
            sc = __builtin_amdgcn_mfma_f32_16x16x32_bf16(qf1, kb1, sc, 0, 0, 0);
            s[c] = sc;
        }

        // exp2 + per-lane l accumulate; causal mask only on the diagonal tile
        if (t == qb) {
#pragma unroll
            for (int r = 0; r < 4; ++r) {
                int qr = q0 + wave * 16 + quad * 4 + r;
#pragma unroll
                for (int c = 0; c < 4; ++c) {
                    int kvi = kv0 + c * 16 + l15;
                    float p = __builtin_amdgcn_exp2f(s[c][r]);
                    p = (kvi > qr) ? 0.f : p;
                    s[c][r] = p;
                    l_r[r] += p;
                }
            }
        } else {
#pragma unroll
            for (int r = 0; r < 4; ++r)
#pragma unroll
                for (int c = 0; c < 4; ++c) {
                    float p = __builtin_amdgcn_exp2f(s[c][r]);
                    s[c][r] = p;
                    l_r[r] += p;
                }
        }

        // P: C/D -> A layout via per-wave LDS (wave-synchronous, no barrier)
#pragma unroll
        for (int c = 0; c < 4; ++c) {
            int pk01, pk23;
            asm("v_cvt_pk_bf16_f32 %0, %1, %2" : "=v"(pk01) : "v"(s[c][0]), "v"(s[c][1]));
            asm("v_cvt_pk_bf16_f32 %0, %1, %2" : "=v"(pk23) : "v"(s[c][2]), "v"(s[c][3]));
            short* pp = &Ps[wave][(quad * 4) * 72 + c * 16 + l15];
            pp[0]   = (short)pk01;
            pp[72]  = (short)(((unsigned)pk01) >> 16);
            pp[144] = (short)pk23;
            pp[216] = (short)(((unsigned)pk23) >> 16);
        }

#pragma unroll
        for (int kk = 0; kk < 64; kk += 32) {
            short8 pf = *(const short8*)&Ps[wave][l15 * 72 + kk + quad * 8];
#pragma unroll
            for (int d = 0; d < 4; ++d) {
                short8 vf = *(const short8*)&Vs[buf][(d * 16 + l15) * 64 + ((kk + quad * 8) ^ xkey)];
                oacc[d] = __builtin_amdgcn_mfma_f32_16x16x32_bf16(pf, vf, oacc[d], 0, 0, 0);
            }
        }
        __syncthreads();   // single barrier per KV tile (drains gl_lds too)
    }

    // deferred l reduction: sum over the 16-lane group (one row each)
    float lsum[4];
#pragma unroll
    for (int r = 0; r < 4; ++r) {
        float l = l_r[r];
#pragma unroll
        for (int off = 8; off > 0; off >>= 1) l += __shfl_xor(l, off, 16);
        lsum[r] = l;
    }

    if (!SPLIT || nc == 1) {
        // single chunk: normalize and write final bf16 O
#pragma unroll
        for (int d = 0; d < 4; ++d)
#pragma unroll
            for (int r = 0; r < 4; ++r) {
                int qr = q0 + wave * 16 + quad * 4 + r;
                O[(size_t)(b * T_ + qr) * D_ + h * 64 + d * 16 + l15] = f2b(oacc[d][r] / lsum[r]);
            }
    } else {
        // chunked: emit unnormalized fp32 partial + l
        const int slot = bh * 72 + chunk_base(qb) + ci;
        float* op = OP + (size_t)slot * 4096;
#pragma unroll
        for (int d = 0; d < 4; ++d)
#pragma unroll
            for (int r = 0; r < 4; ++r)
                op[(wave * 16 + quad * 4 + r) * 64 + d * 16 + l15] = oacc[d][r];
        if (l15 == 0) {
#pragma unroll
            for (int r = 0; r < 4; ++r)
                LP[slot * 64 + wave * 16 + quad * 4 + r] = lsum[r];
        }
    }
}

// --- combine KV-chunk partials: O = (sum_c O_c) / (sum_c l_c), bf16 out ------
__global__ __launch_bounds__(256) void comb_k(const float* __restrict__ OP,
                                              const float* __restrict__ LP,
                                              bf16* __restrict__ O) {
    const int qb = 8 + (int)blockIdx.x;              // only qb>=8 were chunked
    const int bh = blockIdx.y, b = bh >> 4, h = bh & 15;
    const int nc = (qb >> 3) + 1;                    // 2..4 chunks
    const int slot0 = bh * 72 + chunk_base(qb);
    const int tid = threadIdx.x;
    const int row = tid >> 2, c0 = (tid & 3) << 4;   // 16 floats per thread
    const float* p = OP + (size_t)slot0 * 4096 + row * 64 + c0;
    float4_ a0 = *(const float4_*)(p + 0);
    float4_ a1 = *(const float4_*)(p + 4);
    float4_ a2 = *(const float4_*)(p + 8);
    float4_ a3 = *(const float4_*)(p + 12);
    float l = LP[slot0 * 64 + row];
    for (int c = 1; c < nc; ++c) {
        const float* q = p + (size_t)c * 4096;
        a0 += *(const float4_*)(q + 0);
        a1 += *(const float4_*)(q + 4);
        a2 += *(const float4_*)(q + 8);
        a3 += *(const float4_*)(q + 12);
        l += LP[(slot0 + c) * 64 + row];
    }
    float inv = 1.f / l;
    short8 w0, w1;
#pragma unroll
    for (int j = 0; j < 4; ++j) {
        w0[j]     = f2s(a0[j] * inv);
        w0[4 + j] = f2s(a1[j] * inv);
        w1[j]     = f2s(a2[j] * inv);
        w1[4 + j] = f2s(a3[j] * inv);
    }
    bf16* o = O + (size_t)(b * T_ + qb * 64 + row) * D_ + h * 64 + c0;
    *(short8*)o       = w0;
    *(short8*)(o + 8) = w1;
}

// ---------------------------------------------------------------------------
// Workspace:
//   Ah[0,8) ; QKp[8,24) ([NTOK][2048] bf16 q|k) ; VT4[24,32) ([1024][4096]) ;
//   AO[32,40) ; after attn+o-proj: AE1[8,16) AES[16,24) MOD[24,40) ;
//   M1G[8,40) after modnorm.
//   weights [40,70): WTqkv 40 WTo 46 WTae2 48 WTmod 50 WTm1 54 WTm2 62
//   biasQK at 70MB; OPART at 70MB+16K (2304*16KB); LPART after (576KB).
//   X1 (fp32 residual) lives in d_out.
extern "C" void kernel_launch(void* const* d_in, const int* in_sizes, int n_in,
                              void* d_out, int out_size, void* d_ws, size_t ws_size,
                              hipStream_t stream) {
    const float* x     = (const float*)d_in[0];
    const float* acts  = (const float*)d_in[1];
    const float* n1_w  = (const float*)d_in[2];
    const float* n2_w  = (const float*)d_in[3];
    const float* q_w   = (const float*)d_in[4];
    const float* q_b   = (const float*)d_in[5];
    const float* k_w   = (const float*)d_in[6];
    const float* k_b   = (const float*)d_in[7];
    const float* v_w   = (const float*)d_in[8];
    const float* v_b   = (const float*)d_in[9];
    const float* qn_w  = (const float*)d_in[10];
    const float* kn_w  = (const float*)d_in[11];
    const float* o_w   = (const float*)d_in[12];
    const float* o_b   = (const float*)d_in[13];
    const float* ae1_w = (const float*)d_in[14];
    const float* ae1_b = (const float*)d_in[15];
    const float* ae2_w = (const float*)d_in[16];
    const float* ae2_b = (const float*)d_in[17];
    const float* mod_w = (const float*)d_in[18];
    const float* mod_b = (const float*)d_in[19];
    const float* m1_w  = (const float*)d_in[20];
    const float* m1_b  = (const float*)d_in[21];
    const float* m2_w  = (const float*)d_in[22];
    const float* m2_b  = (const float*)d_in[23];
    float* out = (float*)d_out;

    char* ws = (char*)d_ws;
    const size_t MB = 1ull << 20;
    bf16*  Ah   = (bf16*)(ws + 0);
    bf16*  QKp  = (bf16*)(ws + 8 * MB);    // [NTOK][2048]
    bf16*  VT4  = (bf16*)(ws + 24 * MB);   // [1024][4096]
    bf16*  AO   = (bf16*)(ws + 32 * MB);
    bf16*  AE1  = (bf16*)(ws + 8 * MB);
    bf16*  AES  = (bf16*)(ws + 16 * MB);
    bf16*  MOD  = (bf16*)(ws + 24 * MB);
    bf16*  M1G  = (bf16*)(ws + 8 * MB);
    float* X1   = out;

    bf16* WTqkv = (bf16*)(ws + 40 * MB);   // q|k|v contiguous -> [3072][1024]
    bf16* WTv   = WTqkv + 2048 * 1024;
    bf16* WTo   = (bf16*)(ws + 46 * MB);
    bf16* WTae2 = (bf16*)(ws + 48 * MB);
    bf16* WTmod = (bf16*)(ws + 50 * MB);   // [2048][1024]
    bf16* WTm1  = (bf16*)(ws + 54 * MB);   // [4096][1024]
    bf16* WTm2  = (bf16*)(ws + 62 * MB);   // [1024][4096]
    float* biasQK = (float*)(ws + 70 * MB);
    float* OPART  = (float*)(ws + 70 * MB + 16384);            // 2304 * 16 KB
    float* LPART  = (float*)(ws + 70 * MB + 16384 + 37748736); // 2304 * 256 B
    const bool split = ws_size >= (70 * MB + 16384 + 37748736ull + 589824ull);

    dim3 blk(256);

    WPack p;
    p.d[0] = { q_w,   WTqkv,                1024, 1024, 1024, 256 };
    p.d[1] = { k_w,   WTqkv + 1024 * 1024,  1024, 1024, 1024, 256 };
    p.d[2] = { v_w,   WTqkv + 2048 * 1024,  1024, 1024, 1024, 256 };
    p.d[3] = { o_w,   WTo,   1024, 1024, 1024, 256 };
    p.d[4] = { ae2_w, WTae2, 1024, 1024, 1024, 256 };
    p.d[5] = { mod_w, WTmod, 1024, 2048, 4096, 512 };
    p.d[6] = { m1_w,  WTm1,  1024, 4096, 4096, 1024 };
    p.d[7] = { m2_w,  WTm2,  4096, 1024, 1024, 1024 };
    wprep_k<<<3840, blk, 0, stream>>>(p);
    bcat_k<<<8, blk, 0, stream>>>(q_b, k_b, biasQK);

    rmsnorm_k<<<NTOK, blk, 0, stream>>>(x, n1_w, Ah);
    // Q|K projection + fused per-head RMSNorm (q side folds QSCALE)
    gemm_k<0, 1, 0, float, bf16><<<dim3(16, 32), blk, 0, stream>>>(Ah, WTqkv, biasQK, (const float*)nullptr, QKp, NTOK, 2048, 1024, 2048, qn_w, kn_w);
    // V^T = WTv @ Ah^T : [1024 v-cols][4096 tokens], bias per row
    gemm_k<0, 0, 1, float, bf16><<<dim3(32, 8), blk, 0, stream>>>(WTv, Ah, v_b, (const float*)nullptr, VT4, 1024, 4096, 1024, 4096, nullptr, nullptr);
    if (split) {
        attn_k<1><<<dim3(80, B_ * H_), blk, 0, stream>>>(QKp, VT4, AO, OPART, LPART);
        comb_k<<<dim3(24, B_ * H_), blk, 0, stream>>>(OPART, LPART, AO);
    } else {
        attn_k<0><<<dim3(32, B_ * H_), blk, 0, stream>>>(QKp, VT4, AO, OPART, LPART);
    }
    gemm64_k<0, float, float><<<dim3(8, 64), blk, 0, stream>>>(AO, WTo, o_b, x, X1, NTOK, 1024, 1024);
    ae1_k<<<NTOK, blk, 0, stream>>>(acts, ae1_w, ae1_b, AE1);
    gemm64_k<1, float, bf16><<<dim3(8, 64), blk, 0, stream>>>(AE1, WTae2, ae2_b, (const float*)nullptr, AES, NTOK, 1024, 1024);
    gemm_k<0, 0, 0, float, bf16><<<dim3(16, 32), blk, 0, stream>>>(AES, WTmod, mod_b, (const float*)nullptr, MOD, NTOK, 2048, 1024, 2048, nullptr, nullptr);
    modnorm_k<<<NTOK, blk, 0, stream>>>(X1, MOD, n2_w, Ah);
    gemm_k<2, 0, 0, float, bf16><<<dim3(32, 32), blk, 0, stream>>>(Ah, WTm1, m1_b, (const float*)nullptr, M1G, NTOK, 4096, 1024, 4096, nullptr, nullptr);
    gemm64_k<0, float, float><<<dim3(8, 64), blk, 0, stream>>>(M1G, WTm2, m2_b, X1, out, NTOK, 1024, 4096);
}

// Round 5
// 522.018 us; speedup vs baseline: 1.1865x; 1.0032x over previous
//
#include <hip/hip_runtime.h>
#include <hip/hip_bf16.h>
#include <math.h>

typedef __hip_bfloat16 bf16;
typedef __attribute__((ext_vector_type(8))) short short8;
typedef __attribute__((ext_vector_type(4))) float float4_;

#define B_   2
#define T_   2048
#define D_   1024
#define H_   16
#define NTOK (B_ * T_)
// 0.125 * log2(e): folded into q-side RMSNorm weight so attn uses raw exp2.
#define QSCALE 0.18033688011112042f

#define AS1 __attribute__((address_space(1)))
#define AS3 __attribute__((address_space(3)))

static __device__ __forceinline__ float b2f(bf16 v) { return __bfloat162float(v); }
static __device__ __forceinline__ bf16  f2b(float v) { return __float2bfloat16(v); }
static __device__ __forceinline__ short f2s(float v) {  // fp32 -> bf16 bits (RNE)
    unsigned u = __builtin_bit_cast(unsigned, v);
    unsigned r = (u + 0x7FFFu + ((u >> 16) & 1u)) >> 16;
    return (short)r;
}
static __device__ __forceinline__ float to_f(float v) { return v; }
static __device__ __forceinline__ float to_f(bf16 v) { return __bfloat162float(v); }
static __device__ __forceinline__ void  store_o(float* p, float v) { *p = v; }
static __device__ __forceinline__ void  store_o(bf16* p, float v) { *p = __float2bfloat16(v); }
static __device__ __forceinline__ void gl_lds16(const void* g, void* l) {
    __builtin_amdgcn_global_load_lds((const AS1 unsigned int*)g, (AS3 unsigned int*)l, 16, 0, 0);
}
// XCD-chunked block remap (T1): each XCD gets a contiguous chunk of the
// flattened work ids; consecutive w share blockIdx.y-equivalent (bm) so the
// bx-panel stays L2-resident per XCD. Requires gridDim.x*gridDim.y % 8 == 0.
static __device__ __forceinline__ void xcd_remap(int& bx, int& by) {
    int gx = gridDim.x, gy = gridDim.y;
    int flat = (int)blockIdx.y * gx + (int)blockIdx.x;
    int n = gx * gy;
    int w = (flat & 7) * (n >> 3) + (flat >> 3);
    bx = w / gy; by = w - bx * gy;
}

// ---------------- RMSNorm over D=1024 (one block per token), fp32 in, bf16 out
__global__ __launch_bounds__(256) void rmsnorm_k(const float* __restrict__ x,
                                                 const float* __restrict__ w,
                                                 bf16* __restrict__ out) {
    int t = blockIdx.x, tid = threadIdx.x;
    float xs[4], ss = 0.f;
#pragma unroll
    for (int i = 0; i < 4; ++i) {
        float v = x[(size_t)t * D_ + tid + i * 256];
        xs[i] = v; ss += v * v;
    }
    __shared__ float red[4];
#pragma unroll
    for (int off = 32; off > 0; off >>= 1) ss += __shfl_xor(ss, off, 64);
    if ((tid & 63) == 0) red[tid >> 6] = ss;
    __syncthreads();
    ss = red[0] + red[1] + red[2] + red[3];
    float inv = rsqrtf(ss * (1.f / D_) + 1e-6f);
#pragma unroll
    for (int i = 0; i < 4; ++i) {
        int c = tid + i * 256;
        out[(size_t)t * D_ + c] = f2b(xs[i] * inv * w[c]);
    }
}

// ------- fused modulate (x = x*(1+scale1)+shift1, in place fp32) + RMSNorm2 --
__global__ __launch_bounds__(256) void modnorm_k(float* __restrict__ x1,
                                                 const bf16* __restrict__ mod, // [NTOK][2048] = shift|scale
                                                 const float* __restrict__ w,
                                                 bf16* __restrict__ h2) {
    int t = blockIdx.x, tid = threadIdx.x;
    float xs[4], ss = 0.f;
#pragma unroll
    for (int i = 0; i < 4; ++i) {
        int c = tid + i * 256;
        float sh = b2f(mod[(size_t)t * 2048 + c]);
        float sc = b2f(mod[(size_t)t * 2048 + 1024 + c]);
        float v = x1[(size_t)t * D_ + c] * (1.f + sc) + sh;
        xs[i] = v; ss += v * v;
        x1[(size_t)t * D_ + c] = v;
    }
    __shared__ float red[4];
#pragma unroll
    for (int off = 32; off > 0; off >>= 1) ss += __shfl_xor(ss, off, 64);
    if ((tid & 63) == 0) red[tid >> 6] = ss;
    __syncthreads();
    ss = red[0] + red[1] + red[2] + red[3];
    float inv = rsqrtf(ss * (1.f / D_) + 1e-6f);
#pragma unroll
    for (int i = 0; i < 4; ++i) {
        int c = tid + i * 256;
        h2[(size_t)t * D_ + c] = f2b(xs[i] * inv * w[c]);
    }
}

// ------------- ae1: [NTOK,16] @ [16,1024] + b, SiLU (fp32 in, bf16 out) -----
__global__ __launch_bounds__(256) void ae1_k(const float* __restrict__ actions,
                                             const float* __restrict__ w,
                                             const float* __restrict__ b,
                                             bf16* __restrict__ out) {
    int t = blockIdx.x, tid = threadIdx.x;
    float av[16];
#pragma unroll
    for (int a = 0; a < 16; ++a) av[a] = actions[(size_t)t * 16 + a];
#pragma unroll
    for (int i = 0; i < 4; ++i) {
        int n = tid + i * 256;
        float acc = b[n];
#pragma unroll
        for (int a = 0; a < 16; ++a) acc += av[a] * w[a * D_ + n];
        out[(size_t)t * D_ + n] = f2b(acc / (1.f + expf(-acc)));
    }
}

// ---- weight prep: fp32 W[K][N] (row stride ldw) -> bf16 WT[N][K], fused -----
struct WD { const float* src; bf16* dst; int K, N, ldw, tiles; };
struct WPack { WD d[8]; };
__global__ __launch_bounds__(256) void wprep_k(WPack p) {
    int bid = blockIdx.x;
    int mi = 0, cum = 0;
#pragma unroll
    for (mi = 0; mi < 8; ++mi) {
        if (bid < cum + p.d[mi].tiles) break;
        cum += p.d[mi].tiles;
    }
    if (mi >= 8) return;
    WD w = p.d[mi];
    int local = bid - cum;
    int tilesK = w.K >> 6;
    int tk = local % tilesK, tn = local / tilesK;
    int k0 = tk * 64, n0 = tn * 64;
    __shared__ short Tt[64 * 72];   // [n][k]
    int t = threadIdx.x;
    int row = t >> 2, seg = t & 3;
    const float* sp = w.src + (size_t)(k0 + row) * w.ldw + n0 + seg * 16;
#pragma unroll
    for (int q = 0; q < 4; ++q) {
        float4_ f = *(const float4_*)(sp + q * 4);
#pragma unroll
        for (int j = 0; j < 4; ++j) Tt[(seg * 16 + q * 4 + j) * 72 + row] = f2s(f[j]);
    }
    __syncthreads();
    bf16* dp = w.dst + (size_t)(n0 + row) * w.K + k0 + seg * 16;
    *(short8*)dp       = *(const short8*)&Tt[row * 72 + seg * 16];
    *(short8*)(dp + 8) = *(const short8*)&Tt[row * 72 + seg * 16 + 8];
}

// ---- concat q_b|k_b -> biasQK[2048] -----------------------------------------
__global__ __launch_bounds__(256) void bcat_k(const float* __restrict__ qb,
                                              const float* __restrict__ kb,
                                              float* __restrict__ dst) {
    int i = blockIdx.x * 256 + threadIdx.x;   // grid 8*256 = 2048
    dst[i] = (i < 1024) ? qb[i] : kb[i & 1023];
}

// --------- MFMA GEMM 128x128: C = A[M,K](bf16) @ WT[N,K](bf16) ---------------
// ACT: 0 none, 1 SiLU, 2 GELU(exact). res added after ACT. ldo = out/res stride.
// QKN: fused per-head RMSNorm (HD=64) on packed Q|K output; each wave's 64-col
// span is one head, so a 16-lane shuffle gives the head sum-sq. q-head norm
// weight additionally folds QSCALE so attention softmax is bare exp2.
template <int ACT, int QKN, typename ResT, typename OutT>
__global__ __launch_bounds__(256) void gemm_k(const bf16* __restrict__ A,
                                              const bf16* __restrict__ Bt,
                                              const float* __restrict__ bias,
                                              const ResT* __restrict__ res,
                                              OutT* __restrict__ out,
                                              int M, int N, int K, int ldo,
                                              const float* __restrict__ qn_w,
                                              const float* __restrict__ kn_w) {
    __shared__ __align__(16) short As[128 * 64];
    __shared__ __align__(16) short Bs[128 * 64];
    const int tid = threadIdx.x;
    int bxi, byi; xcd_remap(bxi, byi);
    const int bm = byi * 128, bn = bxi * 128;
    const int wave = tid >> 6, lane = tid & 63;
    const int wm = (wave & 1) * 64, wn = (wave >> 1) * 64;
    const int l15 = lane & 15, quad = lane >> 4;
    const int lrow = lane >> 3, lseg = (lane & 7) * 8;
    float4_ acc[4][4] = {};

    for (int k0 = 0; k0 < K; k0 += 64) {
#pragma unroll
        for (int it = 0; it < 4; ++it) {
            int r = it * 32 + wave * 8;
            gl_lds16((const short*)A + (size_t)(bm + r + lrow) * K + k0 + lseg, &As[r * 64]);
            gl_lds16((const short*)Bt + (size_t)(bn + r + lrow) * K + k0 + lseg, &Bs[r * 64]);
        }
        __syncthreads();
#pragma unroll
        for (int kk = 0; kk < 64; kk += 32) {
            short8 af[4], bfr[4];
#pragma unroll
            for (int i = 0; i < 4; ++i)
                af[i] = *(const short8*)&As[(wm + i * 16 + l15) * 64 + kk + quad * 8];
#pragma unroll
            for (int j = 0; j < 4; ++j)
                bfr[j] = *(const short8*)&Bs[(wn + j * 16 + l15) * 64 + kk + quad * 8];
#pragma unroll
            for (int i = 0; i < 4; ++i)
#pragma unroll
                for (int j = 0; j < 4; ++j)
                    acc[i][j] = __builtin_amdgcn_mfma_f32_16x16x32_bf16(af[i], bfr[j], acc[i][j], 0, 0, 0);
        }
        __syncthreads();
    }

    int seg = (bn + wn) >> 10;               // QKN: 0=q, 1=k
    float nwv[4];
    if (QKN && seg < 2) {
        const float* nw = seg ? kn_w : qn_w;
        float qsc = seg ? 1.f : QSCALE;
#pragma unroll
        for (int j = 0; j < 4; ++j) nwv[j] = nw[j * 16 + l15] * qsc;
    }

#pragma unroll
    for (int i = 0; i < 4; ++i) {
        float vv[4][4];
#pragma unroll
        for (int j = 0; j < 4; ++j) {
            float bv = bias[bn + wn + j * 16 + l15];
#pragma unroll
            for (int r = 0; r < 4; ++r) vv[j][r] = acc[i][j][r] + bv;
        }
        if (QKN && seg < 2) {
#pragma unroll
            for (int r = 0; r < 4; ++r) {
                float ss = vv[0][r] * vv[0][r] + vv[1][r] * vv[1][r]
                         + vv[2][r] * vv[2][r] + vv[3][r] * vv[3][r];
#pragma unroll
                for (int off = 8; off > 0; off >>= 1) ss += __shfl_xor(ss, off, 16);
                float inv = rsqrtf(ss * (1.f / 64.f) + 1e-6f);
#pragma unroll
                for (int j = 0; j < 4; ++j) vv[j][r] *= inv * nwv[j];
            }
        }
#pragma unroll
        for (int j = 0; j < 4; ++j) {
            int col = bn + wn + j * 16 + l15;
#pragma unroll
            for (int r = 0; r < 4; ++r) {
                int row = bm + wm + i * 16 + quad * 4 + r;
                float v = vv[j][r];
                if (ACT == 1) v = v / (1.f + expf(-v));
                else if (ACT == 2) v = 0.5f * v * (1.f + erff(v * 0.70710678118654752f));
                if (res) v += to_f(res[(size_t)row * ldo + col]);
                store_o(&out[(size_t)row * ldo + col], v);
            }
        }
    }
}

// --------- MFMA GEMM 64x128 tile: for N=1024 GEMMs (512 blocks = 2/CU) -------
// BROW: bias indexed by ROW (for the V^T = Wv^T @ h^T GEMM).
template <int ACT, int BROW, typename ResT, typename OutT>
__global__ __launch_bounds__(256) void gemm64_k(const bf16* __restrict__ A,
                                                const bf16* __restrict__ Bt,
                                                const float* __restrict__ bias,
                                                const ResT* __restrict__ res,
                                                OutT* __restrict__ out,
                                                int M, int N, int K) {
    __shared__ __align__(16) short As[64 * 64];
    __shared__ __align__(16) short Bs[128 * 64];
    const int tid = threadIdx.x;
    int bxi, byi; xcd_remap(bxi, byi);
    const int bm = byi * 64, bn = bxi * 128;
    const int wave = tid >> 6, lane = tid & 63;
    const int wm = (wave & 1) * 32, wn = (wave >> 1) * 64;
    const int l15 = lane & 15, quad = lane >> 4;
    const int lrow = lane >> 3, lseg = (lane & 7) * 8;
    float4_ acc[2][4] = {};

    for (int k0 = 0; k0 < K; k0 += 64) {
#pragma unroll
        for (int it = 0; it < 2; ++it) {
            int r = wave * 16 + it * 8;
            gl_lds16((const short*)A + (size_t)(bm + r + lrow) * K + k0 + lseg, &As[r * 64]);
        }
#pragma unroll
        for (int it = 0; it < 4; ++it) {
            int r = it * 32 + wave * 8;
            gl_lds16((const short*)Bt + (size_t)(bn + r + lrow) * K + k0 + lseg, &Bs[r * 64]);
        }
        __syncthreads();
#pragma unroll
        for (int kk = 0; kk < 64; kk += 32) {
            short8 af[2], bfr[4];
#pragma unroll
            for (int i = 0; i < 2; ++i)
                af[i] = *(const short8*)&As[(wm + i * 16 + l15) * 64 + kk + quad * 8];
#pragma unroll
            for (int j = 0; j < 4; ++j)
                bfr[j] = *(const short8*)&Bs[(wn + j * 16 + l15) * 64 + kk + quad * 8];
#pragma unroll
            for (int i = 0; i < 2; ++i)
#pragma unroll
                for (int j = 0; j < 4; ++j)
                    acc[i][j] = __builtin_amdgcn_mfma_f32_16x16x32_bf16(af[i], bfr[j], acc[i][j], 0, 0, 0);
        }
        __syncthreads();
    }

#pragma unroll
    for (int i = 0; i < 2; ++i) {
        float bvr[4];
        if (BROW) {
#pragma unroll
            for (int r = 0; r < 4; ++r) bvr[r] = bias[bm + wm + i * 16 + quad * 4 + r];
        }
#pragma unroll
        for (int j = 0; j < 4; ++j) {
            int col = bn + wn + j * 16 + l15;
            float bvc = BROW ? 0.f : bias[col];
#pragma unroll
            for (int r = 0; r < 4; ++r) {
                int row = bm + wm + i * 16 + quad * 4 + r;
                float v = acc[i][j][r] + (BROW ? bvr[r] : bvc);
                if (ACT == 1) v = v / (1.f + expf(-v));
                else if (ACT == 2) v = 0.5f * v * (1.f + erff(v * 0.70710678118654752f));
                if (res) v += to_f(res[(size_t)row * N + col]);
                store_o(&out[(size_t)row * N + col], v);
            }
        }
    }
}

// -------------- flash attention, causal, HD=64, q-tile 64, KV tile 64 --------
// R4 structure (K and V both staged via global_load_lds, double-buffered,
// XOR source-swizzle + read-XOR) + XCD-chunked block remap so the ~4 heads in
// each XCD chunk keep their K/V panels L2-resident. NO-MAX softmax
// (qk-RMSNorm bounds |s|), Q pre-scaled by 0.125*log2e -> bare exp2.
// Partial (O,l) combine linearly across KV chunks (nc = qb/8+1).
static __device__ __forceinline__ int chunk_base(int qb) {  // first slot, qb>=8
    return (qb < 16) ? (qb - 8) * 2
         : (qb < 24) ? 16 + (qb - 16) * 3
                     : 40 + (qb - 24) * 4;
}

template <int SPLIT>
__global__ __launch_bounds__(256) void attn_k(const bf16* __restrict__ QK,  // [NTOK][2048] q|k
                                              const bf16* __restrict__ VT,  // [1024][4096]
                                              bf16* __restrict__ O,
                                              float* __restrict__ OP,
                                              float* __restrict__ LP) {
    __shared__ __align__(16) short Ks[2][64 * 64];  // [kv][hd], XOR-swizzled blocks
    __shared__ __align__(16) short Vs[2][64 * 64];  // [hd][kv], XOR-swizzled blocks
    __shared__ __align__(16) short Ps[4][16 * 72];  // per-wave [q][kv]
    int bxw, bh; { int t_ = bh; (void)t_; }
    {   // XCD-chunked remap: consecutive w share bh (KV panel L2-resident)
        int gx = gridDim.x;
        int flat = (int)blockIdx.y * gx + (int)blockIdx.x;
        int n = gx * (int)gridDim.y;
        int w = (flat & 7) * (n >> 3) + (flat >> 3);
        bh = w / gx; bxw = w - bh * gx;
    }
    const int b = bh >> 4, h = bh & 15;
    int qb, ci;
    if (SPLIT) {
        int idx = 79 - bxw;                          // big chunks dispatch first
        if (idx < 8)       { qb = idx; ci = 0; }
        else if (idx < 24) { qb = 8 + ((idx - 8) >> 1); ci = (idx - 8) & 1; }
        else if (idx < 48) { int u = idx - 24; int q3 = u / 3; qb = 16 + q3; ci = u - q3 * 3; }
        else               { int u = idx - 48; qb = 24 + (u >> 2); ci = u & 3; }
    } else { qb = 31 - bxw; ci = 0; }
    const int n   = qb + 1;                          // causal KV tiles for qb
    const int nc  = SPLIT ? ((qb >> 3) + 1) : 1;
    const int bsz = n / nc, rem = n - bsz * nc;      // balanced chunk sizes
    const int t0  = ci * bsz + (ci < rem ? ci : rem);
    const int t1  = t0 + bsz + (ci < rem ? 1 : 0);
    const int q0  = qb * 64;
    const int tid = threadIdx.x, wave = tid >> 6, lane = tid & 63;
    const int l15 = lane & 15, quad = lane >> 4;

    const short* Qp  = (const short*)QK + (size_t)b * T_ * 2048 + h * 64;
    const short* Kp  = Qp + 1024;
    const short* Vtp = (const short*)VT + (size_t)h * 64 * 4096 + b * T_;

    const int qrow = q0 + wave * 16 + l15;
    short8 qf0 = *(const short8*)(Qp + (size_t)qrow * 2048 + quad * 8);
    short8 qf1 = *(const short8*)(Qp + (size_t)qrow * 2048 + 32 + quad * 8);

    float4_ oacc[4] = {};
    float l_r[4] = {0.f, 0.f, 0.f, 0.f};

    const int slr  = lane >> 3;                      // row within 8-row group
    const int sblk = (lane & 7) ^ slr;               // pre-swizzled source block

    // stage K+V tile t into buffer bb (global_load_lds, swizzled source)
#define STAGE_KV(t, bb)                                                          \
    {                                                                            \
        _Pragma("unroll")                                                        \
        for (int it = 0; it < 2; ++it) {                                         \
            int r = it * 32 + wave * 8;                                          \
            gl_lds16(Kp + (size_t)((t) * 64 + r + slr) * 2048 + sblk * 8, &Ks[bb][r * 64]); \
            gl_lds16(Vtp + (size_t)(r + slr) * 4096 + (t) * 64 + sblk * 8, &Vs[bb][r * 64]); \
        }                                                                        \
    }

    STAGE_KV(t0, 0);
    __syncthreads();

    const int xkey = (l15 & 7) * 8;                  // read-side XOR (shorts)

    for (int t = t0; t < t1; ++t) {
        const int kv0 = t * 64, buf = (t - t0) & 1;
        if (t + 1 < t1) STAGE_KV(t + 1, buf ^ 1);    // prefetch next tile

        // QK^T: K fragments from LDS (swizzled, conflict-free)
        float4_ s[4];
#pragma unroll
        for (int c = 0; c < 4; ++c) {
            const short* kr = &Ks[buf][(c * 16 + l15) * 64];
            short8 kb0 = *(const short8*)&kr[(quad * 8) ^ xkey];
            short8 kb1 = *(const short8*)&kr[(32 + quad * 8) ^ xkey];
            float4_ sc = {};
            sc = __builtin_amdgcn_mfma_f32_16x16x32_bf16(qf0, kb0, sc, 0, 0, 0);
            sc = __builtin_amdgcn_mfma_f32_16x16x32_bf16(qf1, kb1, sc, 0, 0, 0);
            s[c] = sc;
        }

        // exp2 + per-lane l accumulate; causal mask only on the diagonal tile
        if (t == qb) {
#pragma unroll
            for (int r = 0; r < 4; ++r) {
                int qr = q0 + wave * 16 + quad * 4 + r;
#pragma unroll
                for (int c = 0; c < 4; ++c) {
                    int kvi = kv0 + c * 16 + l15;
                    float p = __builtin_amdgcn_exp2f(s[c][r]);
                    p = (kvi > qr) ? 0.f : p;
                    s[c][r] = p;
                    l_r[r] += p;
                }
            }
        } else {
#pragma unroll
            for (int r = 0; r < 4; ++r)
#pragma unroll
                for (int c = 0; c < 4; ++c) {
                    float p = __builtin_amdgcn_exp2f(s[c][r]);
                    s[c][r] = p;
                    l_r[r] += p;
                }
        }

        // P: C/D -> A layout via per-wave LDS (wave-synchronous, no barrier)
#pragma unroll
        for (int c = 0; c < 4; ++c) {
            int pk01, pk23;
            asm("v_cvt_pk_bf16_f32 %0, %1, %2" : "=v"(pk01) : "v"(s[c][0]), "v"(s[c][1]));
            asm("v_cvt_pk_bf16_f32 %0, %1, %2" : "=v"(pk23) : "v"(s[c][2]), "v"(s[c][3]));
            short* pp = &Ps[wave][(quad * 4) * 72 + c * 16 + l15];
            pp[0]   = (short)pk01;
            pp[72]  = (short)(((unsigned)pk01) >> 16);
            pp[144] = (short)pk23;
            pp[216] = (short)(((unsigned)pk23) >> 16);
        }

#pragma unroll
        for (int kk = 0; kk < 64; kk += 32) {
            short8 pf = *(const short8*)&Ps[wave][l15 * 72 + kk + quad * 8];
#pragma unroll
            for (int d = 0; d < 4; ++d) {
                short8 vf = *(const short8*)&Vs[buf][(d * 16 + l15) * 64 + ((kk + quad * 8) ^ xkey)];
                oacc[d] = __builtin_amdgcn_mfma_f32_16x16x32_bf16(pf, vf, oacc[d], 0, 0, 0);
            }
        }
        __syncthreads();   // single barrier per KV tile (drains gl_lds too)
    }

    // deferred l reduction: sum over the 16-lane group (one row each)
    float lsum[4];
#pragma unroll
    for (int r = 0; r < 4; ++r) {
        float l = l_r[r];
#pragma unroll
        for (int off = 8; off > 0; off >>= 1) l += __shfl_xor(l, off, 16);
        lsum[r] = l;
    }

    if (!SPLIT || nc == 1) {
        // single chunk: normalize and write final bf16 O
#pragma unroll
        for (int d = 0; d < 4; ++d)
#pragma unroll
            for (int r = 0; r < 4; ++r) {
                int qr = q0 + wave * 16 + quad * 4 + r;
                O[(size_t)(b * T_ + qr) * D_ + h * 64 + d * 16 + l15] = f2b(oacc[d][r] / lsum[r]);
            }
    } else {
        // chunked: emit unnormalized fp32 partial + l
        const int slot = bh * 72 + chunk_base(qb) + ci;
        float* op = OP + (size_t)slot * 4096;
#pragma unroll
        for (int d = 0; d < 4; ++d)
#pragma unroll
            for (int r = 0; r < 4; ++r)
                op[(wave * 16 + quad * 4 + r) * 64 + d * 16 + l15] = oacc[d][r];
        if (l15 == 0) {
#pragma unroll
            for (int r = 0; r < 4; ++r)
                LP[slot * 64 + wave * 16 + quad * 4 + r] = lsum[r];
        }
    }
}

// --- combine KV-chunk partials: O = (sum_c O_c) / (sum_c l_c), bf16 out ------
__global__ __launch_bounds__(256) void comb_k(const float* __restrict__ OP,
                                              const float* __restrict__ LP,
                                              bf16* __restrict__ O) {
    const int qb = 8 + (int)blockIdx.x;              // only qb>=8 were chunked
    const int bh = blockIdx.y, b = bh >> 4, h = bh & 15;
    const int nc = (qb >> 3) + 1;                    // 2..4 chunks
    const int slot0 = bh * 72 + chunk_base(qb);
    const int tid = threadIdx.x;
    const int row = tid >> 2, c0 = (tid & 3) << 4;   // 16 floats per thread
    const float* p = OP + (size_t)slot0 * 4096 + row * 64 + c0;
    float4_ a0 = *(const float4_*)(p + 0);
    float4_ a1 = *(const float4_*)(p + 4);
    float4_ a2 = *(const float4_*)(p + 8);
    float4_ a3 = *(const float4_*)(p + 12);
    float l = LP[slot0 * 64 + row];
    for (int c = 1; c < nc; ++c) {
        const float* q = p + (size_t)c * 4096;
        a0 += *(const float4_*)(q + 0);
        a1 += *(const float4_*)(q + 4);
        a2 += *(const float4_*)(q + 8);
        a3 += *(const float4_*)(q + 12);
        l += LP[(slot0 + c) * 64 + row];
    }
    float inv = 1.f / l;
    short8 w0, w1;
#pragma unroll
    for (int j = 0; j < 4; ++j) {
        w0[j]     = f2s(a0[j] * inv);
        w0[4 + j] = f2s(a1[j] * inv);
        w1[j]     = f2s(a2[j] * inv);
        w1[4 + j] = f2s(a3[j] * inv);
    }
    bf16* o = O + (size_t)(b * T_ + qb * 64 + row) * D_ + h * 64 + c0;
    *(short8*)o       = w0;
    *(short8*)(o + 8) = w1;
}

// ---------------------------------------------------------------------------
// Workspace:
//   Ah[0,8) ; QKp[8,24) ([NTOK][2048] bf16 q|k) ; VT4[24,32) ([1024][4096]) ;
//   AO[32,40) ; after attn+o-proj: AE1[8,16) AES[16,24) MOD[24,40) ;
//   M1G[8,40) after modnorm.
//   weights [40,70): WTqkv 40 WTo 46 WTae2 48 WTmod 50 WTm1 54 WTm2 62
//   biasQK at 70MB; OPART at 70MB+16K (2304*16KB); LPART after (576KB).
//   X1 (fp32 residual) lives in d_out.
extern "C" void kernel_launch(void* const* d_in, const int* in_sizes, int n_in,
                              void* d_out, int out_size, void* d_ws, size_t ws_size,
                              hipStream_t stream) {
    const float* x     = (const float*)d_in[0];
    const float* acts  = (const float*)d_in[1];
    const float* n1_w  = (const float*)d_in[2];
    const float* n2_w  = (const float*)d_in[3];
    const float* q_w   = (const float*)d_in[4];
    const float* q_b   = (const float*)d_in[5];
    const float* k_w   = (const float*)d_in[6];
    const float* k_b   = (const float*)d_in[7];
    const float* v_w   = (const float*)d_in[8];
    const float* v_b   = (const float*)d_in[9];
    const float* qn_w  = (const float*)d_in[10];
    const float* kn_w  = (const float*)d_in[11];
    const float* o_w   = (const float*)d_in[12];
    const float* o_b   = (const float*)d_in[13];
    const float* ae1_w = (const float*)d_in[14];
    const float* ae1_b = (const float*)d_in[15];
    const float* ae2_w = (const float*)d_in[16];
    const float* ae2_b = (const float*)d_in[17];
    const float* mod_w = (const float*)d_in[18];
    const float* mod_b = (const float*)d_in[19];
    const float* m1_w  = (const float*)d_in[20];
    const float* m1_b  = (const float*)d_in[21];
    const float* m2_w  = (const float*)d_in[22];
    const float* m2_b  = (const float*)d_in[23];
    float* out = (float*)d_out;

    char* ws = (char*)d_ws;
    const size_t MB = 1ull << 20;
    bf16*  Ah   = (bf16*)(ws + 0);
    bf16*  QKp  = (bf16*)(ws + 8 * MB);    // [NTOK][2048]
    bf16*  VT4  = (bf16*)(ws + 24 * MB);   // [1024][4096]
    bf16*  AO   = (bf16*)(ws + 32 * MB);
    bf16*  AE1  = (bf16*)(ws + 8 * MB);
    bf16*  AES  = (bf16*)(ws + 16 * MB);
    bf16*  MOD  = (bf16*)(ws + 24 * MB);
    bf16*  M1G  = (bf16*)(ws + 8 * MB);
    float* X1   = out;

    bf16* WTqkv = (bf16*)(ws + 40 * MB);   // q|k|v contiguous -> [3072][1024]
    bf16* WTv   = WTqkv + 2048 * 1024;
    bf16* WTo   = (bf16*)(ws + 46 * MB);
    bf16* WTae2 = (bf16*)(ws + 48 * MB);
    bf16* WTmod = (bf16*)(ws + 50 * MB);   // [2048][1024]
    bf16* WTm1  = (bf16*)(ws + 54 * MB);   // [4096][1024]
    bf16* WTm2  = (bf16*)(ws + 62 * MB);   // [1024][4096]
    float* biasQK = (float*)(ws + 70 * MB);
    float* OPART  = (float*)(ws + 70 * MB + 16384);            // 2304 * 16 KB
    float* LPART  = (float*)(ws + 70 * MB + 16384 + 37748736); // 2304 * 256 B
    const bool split = ws_size >= (70 * MB + 16384 + 37748736ull + 589824ull);

    dim3 blk(256);

    WPack p;
    p.d[0] = { q_w,   WTqkv,                1024, 1024, 1024, 256 };
    p.d[1] = { k_w,   WTqkv + 1024 * 1024,  1024, 1024, 1024, 256 };
    p.d[2] = { v_w,   WTqkv + 2048 * 1024,  1024, 1024, 1024, 256 };
    p.d[3] = { o_w,   WTo,   1024, 1024, 1024, 256 };
    p.d[4] = { ae2_w, WTae2, 1024, 1024, 1024, 256 };
    p.d[5] = { mod_w, WTmod, 1024, 2048, 4096, 512 };
    p.d[6] = { m1_w,  WTm1,  1024, 4096, 4096, 1024 };
    p.d[7] = { m2_w,  WTm2,  4096, 1024, 1024, 1024 };
    wprep_k<<<3840, blk, 0, stream>>>(p);
    bcat_k<<<8, blk, 0, stream>>>(q_b, k_b, biasQK);

    rmsnorm_k<<<NTOK, blk, 0, stream>>>(x, n1_w, Ah);
    // Q|K projection + fused per-head RMSNorm (q side folds QSCALE)
    gemm_k<0, 1, float, bf16><<<dim3(16, 32), blk, 0, stream>>>(Ah, WTqkv, biasQK, (const float*)nullptr, QKp, NTOK, 2048, 1024, 2048, qn_w, kn_w);
    // V^T = WTv @ Ah^T : [1024 v-cols][4096 tokens], bias per row (2 blk/CU)
    gemm64_k<0, 1, float, bf16><<<dim3(32, 16), blk, 0, stream>>>(WTv, Ah, v_b, (const float*)nullptr, VT4, 1024, 4096, 1024);
    if (split) {
        attn_k<1><<<dim3(80, B_ * H_), blk, 0, stream>>>(QKp, VT4, AO, OPART, LPART);
        comb_k<<<dim3(24, B_ * H_), blk, 0, stream>>>(OPART, LPART, AO);
    } else {
        attn_k<0><<<dim3(32, B_ * H_), blk, 0, stream>>>(QKp, VT4, AO, OPART, LPART);
    }
    gemm64_k<0, 0, float, float><<<dim3(8, 64), blk, 0, stream>>>(AO, WTo, o_b, x, X1, NTOK, 1024, 1024);
    ae1_k<<<NTOK, blk, 0, stream>>>(acts, ae1_w, ae1_b, AE1);
    gemm64_k<1, 0, float, bf16><<<dim3(8, 64), blk, 0, stream>>>(AE1, WTae2, ae2_b, (const float*)nullptr, AES, NTOK, 1024, 1024);
    gemm_k<0, 0, float, bf16><<<dim3(16, 32), blk, 0, stream>>>(AES, WTmod, mod_b, (const float*)nullptr, MOD, NTOK, 2048, 1024, 2048, nullptr, nullptr);
    modnorm_k<<<NTOK, blk, 0, stream>>>(X1, MOD, n2_w, Ah);
    gemm_k<2, 0, float, bf16><<<dim3(32, 32), blk, 0, stream>>>(Ah, WTm1, m1_b, (const float*)nullptr, M1G, NTOK, 4096, 1024, 4096, nullptr, nullptr);
    gemm64_k<0, 0, float, float><<<dim3(8, 64), blk, 0, stream>>>(M1G, WTm2, m2_b, X1, out, NTOK, 1024, 4096);
}